// Round 10
// baseline (598.420 us; speedup 1.0000x reference)
//
#include <hip/hip_runtime.h>
#include <math.h>

#define TPB 256
#define NEG_SLOPE 0.2f
#define SCAN_T 1024
#define EPB 2048          // edges per block-chunk in sliced CSR kernels

static inline int cdiv_l(long a, int b){ return (int)((a + b - 1) / b); }

__device__ __forceinline__ ushort f2bf(float f){
  unsigned u = __float_as_uint(f);
  unsigned r = u + 0x7fffu + ((u >> 16) & 1u);   // RNE
  return (ushort)(r >> 16);
}
__device__ __forceinline__ float bf2f(unsigned hi16){ return __uint_as_float(hi16 << 16); }

// ---------------- GEMM + fused attention dots + bf16 payload write ----------------
template<int Fin, int HC, int C>
__global__ __launch_bounds__(256) void gemm2_k(const float* __restrict__ X,
        const float* __restrict__ W, const float* __restrict__ as_,
        const float* __restrict__ ad_, float* __restrict__ es, float* __restrict__ ed,
        ushort* __restrict__ Hb, int N){
  constexpr int TPN = HC / 4;         // threads per node
  constexpr int NPB = 256 / TPN;      // nodes per block
  constexpr int H   = HC / C;
  constexpr int RG  = C / 4;          // lanes per (node, head)
  __shared__ float Wl[Fin * HC];
  for (int i = threadIdx.x; i < Fin * HC; i += 256) Wl[i] = W[i];
  __syncthreads();
  const int t  = threadIdx.x;
  const int n  = blockIdx.x * NPB + t / TPN;
  const int jt = (t % TPN) * 4;
  if (n >= N) return;
  const float* xr = X + (size_t)n * Fin;
  float acc[4] = {0.f, 0.f, 0.f, 0.f};
  for (int k = 0; k < Fin; k += 4){
    float4 xv = *(const float4*)(xr + k);
#pragma unroll
    for (int kk = 0; kk < 4; ++kk){
      float xs = (&xv.x)[kk];
#pragma unroll
      for (int j = 0; j < 4; ++j)
        acc[j] = fmaf(xs, Wl[(k + kk) * HC + jt + j], acc[j]);
    }
  }
  ushort4 hb;
  hb.x = f2bf(acc[0]); hb.y = f2bf(acc[1]); hb.z = f2bf(acc[2]); hb.w = f2bf(acc[3]);
  *(ushort4*)(Hb + (size_t)n * HC + jt) = hb;
  const int head = jt / C, col = jt % C;
  float ps = 0.f, pd = 0.f;
#pragma unroll
  for (int j = 0; j < 4; ++j){
    ps = fmaf(acc[j], as_[head * C + col + j], ps);
    pd = fmaf(acc[j], ad_[head * C + col + j], pd);
  }
#pragma unroll
  for (int off = RG >> 1; off >= 1; off >>= 1){
    ps += __shfl_xor(ps, off);
    pd += __shfl_xor(pd, off);
  }
  if ((t % RG) == 0){
    es[n * H + head] = ps;
    ed[n * H + head] = pd;
  }
}

// ---------------- CSR build (XCD-sliced) ----------------

__global__ __launch_bounds__(256) void hist8_k(const int* __restrict__ dst,
                        int* __restrict__ count, int E, int nps){
  const int slice = blockIdx.x & 7;
  const int lo = slice * nps, hi = lo + nps;
  const int c0 = (blockIdx.x >> 3) * EPB;
  int i1 = c0 + EPB; if (i1 > E) i1 = E;
  for (int i = c0 + threadIdx.x; i < i1; i += TPB){
    int d = __builtin_nontemporal_load(dst + i);
    if (d >= lo && d < hi) atomicAdd(&count[d], 1);
  }
}

// single-block exclusive scan; +1 per node folds in the self-loop
__global__ void scan_k(const int* __restrict__ count, int* __restrict__ row_off, int N){
  __shared__ int part[SCAN_T];
  int t = threadIdx.x;
  int chunk = (N + SCAN_T - 1) / SCAN_T;
  int b0 = t * chunk, b1 = b0 + chunk; if (b1 > N) b1 = N; if (b0 > N) b0 = N;
  int s = 0;
  for (int i = b0; i < b1; ++i) s += count[i] + 1;
  part[t] = s; __syncthreads();
  for (int off = 1; off < SCAN_T; off <<= 1){
    int v = (t >= off) ? part[t - off] : 0;
    __syncthreads();
    part[t] += v;
    __syncthreads();
  }
  int excl = (t == 0) ? 0 : part[t - 1];
  for (int i = b0; i < b1; ++i){ row_off[i] = excl; excl += count[i] + 1; }
  if (t == SCAN_T - 1) row_off[N] = excl;
}

__global__ void cursor_k(const int* __restrict__ row_off, int* __restrict__ cursor,
                         int* __restrict__ csr_src, int N){
  int i = blockIdx.x * TPB + threadIdx.x;
  if (i >= N) return;
  int r = row_off[i];
  csr_src[r] = i;          // self-loop occupies first slot
  cursor[i] = r + 1;
}

// scattered 4B stores miss L2 without write-allocate -> use atomicExch (RMW
// forces L2 ownership), so slice-local lines fill before one writeback.
__global__ __launch_bounds__(256) void scatter8_k(const int* __restrict__ src,
                          const int* __restrict__ dst,
                          int* __restrict__ cursor, int* __restrict__ csr_src,
                          int E, int nps){
  const int slice = blockIdx.x & 7;
  const int lo = slice * nps, hi = lo + nps;
  const int c0 = (blockIdx.x >> 3) * EPB;
  int i1 = c0 + EPB; if (i1 > E) i1 = E;
  for (int i = c0 + threadIdx.x; i < i1; i += TPB){
    int d = __builtin_nontemporal_load(dst + i);
    if (d >= lo && d < hi){
      int s = __builtin_nontemporal_load(src + i);
      int p = atomicAdd(&cursor[d], 1);
      atomicExch(&csr_src[p], s);
    }
  }
}

// ---------------- fused single-pass softmax + aggregate + bias + relu ----------------
// one wave per destination node; bf16 payload, fp32 accumulate.
// t = exp(min(leaky(es+ed),80)) (shift-free softmax); acc += t*h; den += t.
// Wide datapath: each lane owns 4 channels (dwordx2), LPE=HC/4 lanes per edge,
// EPW=64/LPE edges per wave-iteration. Invalid slots carry t=0 -> branch-free.

template<int H, int C>
__global__ __launch_bounds__(256) void agg_k(const int* __restrict__ csr_src,
        const int* __restrict__ row_off,
        const float* __restrict__ es, const float* __restrict__ ed,
        const ushort* __restrict__ Hb, const float* __restrict__ b,
        float* __restrict__ outp, int N){
  constexpr int HC  = H * C;
  constexpr int LPE = HC / 4;         // lanes per edge
  constexpr int EPW = 64 / LPE;       // edges per wave-iteration
  const int lane = threadIdx.x & 63;
  const int wv   = threadIdx.x >> 6;
  const int n = blockIdx.x * 4 + wv;
  if (n >= N) return;
  const int beg = row_off[n];
  const int deg = row_off[n + 1] - beg;

  const int grp  = lane / LPE;        // which edge slot this lane serves
  const int cpos = lane % LPE;        // which 4-channel group
  const int c0   = cpos * 4;
  const int hd   = c0 / C;            // head of this lane's channels (C%4==0)

  float edn[H];
#pragma unroll
  for (int h = 0; h < H; ++h) edn[h] = ed[n * H + h];

  float den[H];
#pragma unroll
  for (int h = 0; h < H; ++h) den[h] = 0.f;
  float acc[4] = {0.f, 0.f, 0.f, 0.f};

  for (int base = 0; base < deg; base += 64){
    int j = base + lane;
    float t[H]; int sidx = 0;
    if (j < deg){
      sidx = csr_src[beg + j];
      float ev[H];
      if (H == 2){
        float2 e2 = *(const float2*)(es + sidx * 2);
        ev[0] = e2.x; ev[1] = e2.y;
      } else ev[0] = es[sidx];
#pragma unroll
      for (int h = 0; h < H; ++h){
        float e = ev[h] + edn[h];
        e = e > 0.f ? e : e * NEG_SLOPE;
        e = fminf(e, 80.f);
        t[h] = __expf(e);
        den[h] += t[h];
      }
    } else {
#pragma unroll
      for (int h = 0; h < H; ++h) t[h] = 0.f;
    }
    int cnt = deg - base; if (cnt > 64) cnt = 64;

    for (int i = 0; i < cnt; i += EPW){
      int sl = i + grp;                       // edge slot for this lane (<64)
      int sj = __shfl(sidx, sl);              // t==0 masks any overrun slot
      float tf;
      if (H == 2){
        float t0 = __shfl(t[0], sl);
        float t1 = __shfl(t[1], sl);
        tf = hd ? t1 : t0;
      } else {
        tf = __shfl(t[0], sl);
      }
      const ushort* hr = Hb + (size_t)sj * HC + c0;
      uint2 v = *(const uint2*)hr;
      acc[0] = fmaf(tf, bf2f(v.x & 0xffffu), acc[0]);
      acc[1] = fmaf(tf, bf2f(v.x >> 16),     acc[1]);
      acc[2] = fmaf(tf, bf2f(v.y & 0xffffu), acc[2]);
      acc[3] = fmaf(tf, bf2f(v.y >> 16),     acc[3]);
    }
  }

  // reduce denominators across the wave
  float sinv[H];
#pragma unroll
  for (int h = 0; h < H; ++h){
    float v = den[h];
#pragma unroll
    for (int off = 32; off >= 1; off >>= 1) v += __shfl_xor(v, off);
    sinv[h] = 1.f / v;
  }

  // reduce partial channel sums across edge-slot groups
#pragma unroll
  for (int off = LPE; off < 64; off <<= 1){
#pragma unroll
    for (int k = 0; k < 4; ++k) acc[k] += __shfl_xor(acc[k], off);
  }

  if (grp == 0){
    float4 bv = *(const float4*)(b + c0);
    float si = sinv[hd];
    float4 o;
    o.x = fmaf(acc[0], si, bv.x); o.x = o.x > 0.f ? o.x : 0.f;
    o.y = fmaf(acc[1], si, bv.y); o.y = o.y > 0.f ? o.y : 0.f;
    o.z = fmaf(acc[2], si, bv.z); o.z = o.z > 0.f ? o.z : 0.f;
    o.w = fmaf(acc[3], si, bv.w); o.w = o.w > 0.f ? o.w : 0.f;
    *(float4*)(outp + (size_t)n * HC + c0) = o;
  }
}

// ---------------- pooling + FC ----------------

__global__ __launch_bounds__(256) void pool_k(const float* __restrict__ f,
                       const int* __restrict__ batch,
                       float* __restrict__ pooled, float* __restrict__ cnt, int N){
  __shared__ float sp[64 * 16];
  __shared__ float sc[64];
  const int t = threadIdx.x;
  for (int i = t; i < 64 * 16; i += 256) sp[i] = 0.f;
  for (int i = t; i < 64; i += 256) sc[i] = 0.f;
  __syncthreads();
  const int per = (N + gridDim.x - 1) / gridDim.x;
  const int n0 = blockIdx.x * per;
  int n1 = n0 + per; if (n1 > N) n1 = N;
  const int nloc = t >> 4, c = t & 15;
  for (int n = n0 + nloc; n < n1; n += 16){
    int g = batch[n];
    atomicAdd(&sp[g * 16 + c], f[(size_t)n * 16 + c]);
    if (c == 0) atomicAdd(&sc[g], 1.f);
  }
  __syncthreads();
  for (int i = t; i < 64 * 16; i += 256) if (sp[i] != 0.f) atomicAdd(&pooled[i], sp[i]);
  for (int i = t; i < 64; i += 256)      if (sc[i] != 0.f) atomicAdd(&cnt[i], sc[i]);
}

__global__ void final_fc_k(const float* __restrict__ pooled, const float* __restrict__ cnt,
                           const float* __restrict__ fcW, const float* __restrict__ fcb,
                           float* __restrict__ outp){
  int g = threadIdx.x;
  if (g >= 64) return;
  float c = cnt[g]; c = c > 1.f ? c : 1.f;
  float inv = 1.0f / c;
  float acc = fcb[0];
  for (int i = 0; i < 16; ++i) acc = fmaf(pooled[g * 16 + i] * inv, fcW[i], acc);
  outp[g] = 1.0f / (1.0f + expf(-acc));
}

// ---------------- driver ----------------

extern "C" void kernel_launch(void* const* d_in, const int* in_sizes, int n_in,
                              void* d_out, int out_size, void* d_ws, size_t ws_size,
                              hipStream_t stream) {
  const float* x    = (const float*)d_in[0];
  const int*  ei    = (const int*)d_in[1];
  const int*  batch = (const int*)d_in[2];

  const int N = in_sizes[0] / 128;
  const int E = in_sizes[1] / 2;

  const int* src = ei;
  const int* dst = ei + E;

  const float* W_[5];  const float* as_[5]; const float* ad_[5]; const float* b_[5];
  for (int l = 0; l < 5; ++l) {
    W_[l]  = (const float*)d_in[3 + 4 * l + 0];
    as_[l] = (const float*)d_in[3 + 4 * l + 1];
    ad_[l] = (const float*)d_in[3 + 4 * l + 2];
    b_[l]  = (const float*)d_in[3 + 4 * l + 3];
  }
  const float* fcW = (const float*)d_in[23];
  const float* fcb = (const float*)d_in[24];
  float* outp = (float*)d_out;

  // workspace layout
  float*  f_buf  = (float*)d_ws;                       // N*128 fp32 (layer output)
  ushort* Hb     = (ushort*)(f_buf + (size_t)N * 128); // N*128 bf16 payload
  float*  es     = (float*)(Hb + (size_t)N * 128);     // N*2
  float*  ed     = es + (size_t)N * 2;                 // N*2
  float*  pooled = ed + (size_t)N * 2;                 // 64*16
  float*  cnt    = pooled + 64 * 16;                   // 64
  int*    count  = (int*)(cnt + 64);                   // N
  int*    row_off= count + N;                          // N+1
  int*    cursor = row_off + N + 1;                    // N
  int*    csr_src= cursor + N;                         // E+N

  // ---- build CSR by destination (XCD-sliced; reused by all 5 layers) ----
  const int nps = (N + 7) / 8;                     // nodes per dst-slice
  const int nch = cdiv_l(E, EPB);                  // edge chunks
  hipMemsetAsync(count, 0, (size_t)N * 4, stream);
  hist8_k<<<nch * 8, TPB, 0, stream>>>(dst, count, E, nps);
  scan_k<<<1, SCAN_T, 0, stream>>>(count, row_off, N);
  cursor_k<<<cdiv_l(N, TPB), TPB, 0, stream>>>(row_off, cursor, csr_src, N);
  scatter8_k<<<nch * 8, TPB, 0, stream>>>(src, dst, cursor, csr_src, E, nps);

  const float* X = x;
  const int gb = cdiv_l(N, 4);

  // layer 1: Fin=128, H=1, C=32
  gemm2_k<128,32,32><<<cdiv_l(N, 1024/32), 256, 0, stream>>>(X, W_[0], as_[0], ad_[0], es, ed, Hb, N);
  agg_k<1,32><<<gb, 256, 0, stream>>>(csr_src, row_off, es, ed, Hb, b_[0], f_buf, N);
  // layer 2: Fin=32, H=2, C=32
  gemm2_k<32,64,32><<<cdiv_l(N, 1024/64), 256, 0, stream>>>(f_buf, W_[1], as_[1], ad_[1], es, ed, Hb, N);
  agg_k<2,32><<<gb, 256, 0, stream>>>(csr_src, row_off, es, ed, Hb, b_[1], f_buf, N);
  // layer 3: Fin=64, H=2, C=64
  gemm2_k<64,128,64><<<cdiv_l(N, 1024/128), 256, 0, stream>>>(f_buf, W_[2], as_[2], ad_[2], es, ed, Hb, N);
  agg_k<2,64><<<gb, 256, 0, stream>>>(csr_src, row_off, es, ed, Hb, b_[2], f_buf, N);
  // layer 4: Fin=128, H=2, C=32
  gemm2_k<128,64,32><<<cdiv_l(N, 1024/64), 256, 0, stream>>>(f_buf, W_[3], as_[3], ad_[3], es, ed, Hb, N);
  agg_k<2,32><<<gb, 256, 0, stream>>>(csr_src, row_off, es, ed, Hb, b_[3], f_buf, N);
  // layer 5: Fin=64, H=2, C=8
  gemm2_k<64,16,8><<<cdiv_l(N, 1024/16), 256, 0, stream>>>(f_buf, W_[4], as_[4], ad_[4], es, ed, Hb, N);
  agg_k<2,8><<<gb, 256, 0, stream>>>(csr_src, row_off, es, ed, Hb, b_[4], f_buf, N);

  // global mean pool (G=64) + FC + sigmoid
  hipMemsetAsync(pooled, 0, (64 * 16 + 64) * 4, stream);
  pool_k<<<64, 256, 0, stream>>>(f_buf, batch, pooled, cnt, N);
  final_fc_k<<<1, 64, 0, stream>>>(pooled, cnt, fcW, fcb, outp);
}

// Round 11
// 540.434 us; speedup vs baseline: 1.1073x; 1.1073x over previous
//
#include <hip/hip_runtime.h>
#include <math.h>

#define TPB 256
#define NEG_SLOPE 0.2f
#define SCAN_T 1024
#define EPB 2048          // edges per block-chunk in streaming CSR kernels
#define BK 512            // nodes per bucket (dst>>9)
#define BPB 8             // blocks per bucket in phase-2 kernels

static inline int cdiv_l(long a, int b){ return (int)((a + b - 1) / b); }

__device__ __forceinline__ ushort f2bf(float f){
  unsigned u = __float_as_uint(f);
  unsigned r = u + 0x7fffu + ((u >> 16) & 1u);   // RNE
  return (ushort)(r >> 16);
}
__device__ __forceinline__ float bf2f(unsigned hi16){ return __uint_as_float(hi16 << 16); }

// ---------------- GEMM + fused attention dots + bf16 payload write ----------------
template<int Fin, int HC, int C>
__global__ __launch_bounds__(256) void gemm2_k(const float* __restrict__ X,
        const float* __restrict__ W, const float* __restrict__ as_,
        const float* __restrict__ ad_, float* __restrict__ es, float* __restrict__ ed,
        ushort* __restrict__ Hb, int N){
  constexpr int TPN = HC / 4;         // threads per node
  constexpr int NPB = 256 / TPN;      // nodes per block
  constexpr int H   = HC / C;
  constexpr int RG  = C / 4;          // lanes per (node, head)
  __shared__ float Wl[Fin * HC];
  for (int i = threadIdx.x; i < Fin * HC; i += 256) Wl[i] = W[i];
  __syncthreads();
  const int t  = threadIdx.x;
  const int n  = blockIdx.x * NPB + t / TPN;
  const int jt = (t % TPN) * 4;
  if (n >= N) return;
  const float* xr = X + (size_t)n * Fin;
  float acc[4] = {0.f, 0.f, 0.f, 0.f};
  for (int k = 0; k < Fin; k += 4){
    float4 xv = *(const float4*)(xr + k);
#pragma unroll
    for (int kk = 0; kk < 4; ++kk){
      float xs = (&xv.x)[kk];
#pragma unroll
      for (int j = 0; j < 4; ++j)
        acc[j] = fmaf(xs, Wl[(k + kk) * HC + jt + j], acc[j]);
    }
  }
  ushort4 hb;
  hb.x = f2bf(acc[0]); hb.y = f2bf(acc[1]); hb.z = f2bf(acc[2]); hb.w = f2bf(acc[3]);
  *(ushort4*)(Hb + (size_t)n * HC + jt) = hb;
  const int head = jt / C, col = jt % C;
  float ps = 0.f, pd = 0.f;
#pragma unroll
  for (int j = 0; j < 4; ++j){
    ps = fmaf(acc[j], as_[head * C + col + j], ps);
    pd = fmaf(acc[j], ad_[head * C + col + j], pd);
  }
#pragma unroll
  for (int off = RG >> 1; off >= 1; off >>= 1){
    ps += __shfl_xor(ps, off);
    pd += __shfl_xor(pd, off);
  }
  if ((t % RG) == 0){
    es[n * H + head] = ps;
    ed[n * H + head] = pd;
  }
}

// ---------------- CSR build: two-phase bucket partition ----------------
// Phase 1: bucket (dst>>9) histogram + partition into packed per-bucket arrays.
// Partition writes are append-only per bucket -> lines fill immediately, write
// back once (fixes the 10x write amplification of direct random scatter).

__global__ __launch_bounds__(256) void bucket_hist_k(const int* __restrict__ dst,
                        int* __restrict__ bcount, int E){
  __shared__ int lh[128];
  const int t = threadIdx.x;
  for (int i = t; i < 128; i += TPB) lh[i] = 0;
  __syncthreads();
  const int c0 = blockIdx.x * EPB;
  int i1 = c0 + EPB; if (i1 > E) i1 = E;
  for (int i = c0 + t; i < i1; i += TPB)
    atomicAdd(&lh[dst[i] >> 9], 1);
  __syncthreads();
  for (int i = t; i < 128; i += TPB)
    if (lh[i]) atomicAdd(&bcount[i], lh[i]);
}

__global__ void bucket_scan_k(const int* __restrict__ bcount,
                              int* __restrict__ bbase, int* __restrict__ bcur, int K){
  __shared__ int v[128];
  const int t = threadIdx.x;     // 128 threads
  int orig = (t < K) ? bcount[t] : 0;
  v[t] = orig; __syncthreads();
  for (int off = 1; off < 128; off <<= 1){
    int y = (t >= off) ? v[t - off] : 0;
    __syncthreads();
    v[t] += y;
    __syncthreads();
  }
  int excl = v[t] - orig;
  if (t < K){ bbase[t] = excl; bcur[t] = excl; }
}

__global__ __launch_bounds__(256) void partition_k(const int* __restrict__ src,
                        const int* __restrict__ dst,
                        int* __restrict__ bcur, unsigned* __restrict__ packed, int E){
  __shared__ int lh[128];     // per-bucket local count, then local rank cursor
  __shared__ int lofs[128];   // global base reserved for this block
  const int t = threadIdx.x;
  for (int i = t; i < 128; i += TPB) lh[i] = 0;
  __syncthreads();
  const int c0 = blockIdx.x * EPB;
  int i1 = c0 + EPB; if (i1 > E) i1 = E;
  for (int i = c0 + t; i < i1; i += TPB)
    atomicAdd(&lh[dst[i] >> 9], 1);
  __syncthreads();
  if (t < 128){
    lofs[t] = lh[t] ? atomicAdd(&bcur[t], lh[t]) : 0;
    lh[t] = 0;
  }
  __syncthreads();
  for (int i = c0 + t; i < i1; i += TPB){
    int d = dst[i], k = d >> 9;
    int r = atomicAdd(&lh[k], 1);                       // LDS rank
    packed[lofs[k] + r] = ((unsigned)src[i] << 9) | (unsigned)(d & 511);
  }
}

// Phase 2: per bucket (8 blocks, same XCD via blockIdx&7): node histogram over
// a 512-node window, then scatter into the bucket's ~68KB csr window.

__device__ __forceinline__ bool bucket_range(const int* bbase, const int* bcur,
        int K, int& k, int& i0, int& i1, int& nb){
  const int slice = blockIdx.x & 7;
  const int q = blockIdx.x >> 3;
  const int kk = q / BPB, c = q % BPB;
  k = kk * 8 + slice;
  if (k >= K) return false;
  const int b0 = bbase[k];
  const int sz = bcur[k] - b0;
  const int per = (sz + BPB - 1) / BPB;
  i0 = b0 + c * per;
  i1 = b0 + sz; if (i0 + per < i1) i1 = i0 + per;
  nb = k << 9;
  return i0 < i1;
}

__global__ __launch_bounds__(256) void nodehist_k(const unsigned* __restrict__ packed,
                        const int* __restrict__ bbase, const int* __restrict__ bcur,
                        int* __restrict__ count, int K){
  int k, i0, i1, nb;
  if (!bucket_range(bbase, bcur, K, k, i0, i1, nb)) return;
  for (int i = i0 + threadIdx.x; i < i1; i += TPB){
    unsigned pk = packed[i];
    atomicAdd(&count[nb + (int)(pk & 511u)], 1);
  }
}

// single-block exclusive scan; +1 per node folds in the self-loop
__global__ void scan_k(const int* __restrict__ count, int* __restrict__ row_off, int N){
  __shared__ int part[SCAN_T];
  int t = threadIdx.x;
  int chunk = (N + SCAN_T - 1) / SCAN_T;
  int b0 = t * chunk, b1 = b0 + chunk; if (b1 > N) b1 = N; if (b0 > N) b0 = N;
  int s = 0;
  for (int i = b0; i < b1; ++i) s += count[i] + 1;
  part[t] = s; __syncthreads();
  for (int off = 1; off < SCAN_T; off <<= 1){
    int v = (t >= off) ? part[t - off] : 0;
    __syncthreads();
    part[t] += v;
    __syncthreads();
  }
  int excl = (t == 0) ? 0 : part[t - 1];
  for (int i = b0; i < b1; ++i){ row_off[i] = excl; excl += count[i] + 1; }
  if (t == SCAN_T - 1) row_off[N] = excl;
}

__global__ void cursor_k(const int* __restrict__ row_off, int* __restrict__ cursor,
                         int* __restrict__ csr_src, int N){
  int i = blockIdx.x * TPB + threadIdx.x;
  if (i >= N) return;
  int r = row_off[i];
  csr_src[r] = i;          // self-loop occupies first slot
  cursor[i] = r + 1;
}

__global__ __launch_bounds__(256) void bscatter_k(const unsigned* __restrict__ packed,
                        const int* __restrict__ bbase, const int* __restrict__ bcur,
                        int* __restrict__ cursor, int* __restrict__ csr_src, int K){
  int k, i0, i1, nb;
  if (!bucket_range(bbase, bcur, K, k, i0, i1, nb)) return;
  for (int i = i0 + threadIdx.x; i < i1; i += TPB){
    unsigned pk = packed[i];
    int d = nb + (int)(pk & 511u);
    int p = atomicAdd(&cursor[d], 1);
    csr_src[p] = (int)(pk >> 9);
  }
}

// ---------------- fused single-pass softmax + aggregate + bias + relu ----------------
// one wave per destination node; bf16 payload, fp32 accumulate.
// t = exp(min(leaky(es+ed),80)) (shift-free softmax); acc += t*h; den += t.
// Wide datapath: each lane owns 4 channels (dwordx2), LPE=HC/4 lanes per edge,
// EPW=64/LPE edges per wave-iteration. Invalid slots carry t=0 -> branch-free.

template<int H, int C>
__global__ __launch_bounds__(256) void agg_k(const int* __restrict__ csr_src,
        const int* __restrict__ row_off,
        const float* __restrict__ es, const float* __restrict__ ed,
        const ushort* __restrict__ Hb, const float* __restrict__ b,
        float* __restrict__ outp, int N){
  constexpr int HC  = H * C;
  constexpr int LPE = HC / 4;         // lanes per edge
  constexpr int EPW = 64 / LPE;       // edges per wave-iteration
  const int lane = threadIdx.x & 63;
  const int wv   = threadIdx.x >> 6;
  const int n = blockIdx.x * 4 + wv;
  if (n >= N) return;
  const int beg = row_off[n];
  const int deg = row_off[n + 1] - beg;

  const int grp  = lane / LPE;        // which edge slot this lane serves
  const int cpos = lane % LPE;        // which 4-channel group
  const int c0   = cpos * 4;
  const int hd   = c0 / C;            // head of this lane's channels (C%4==0)

  float edn[H];
#pragma unroll
  for (int h = 0; h < H; ++h) edn[h] = ed[n * H + h];

  float den[H];
#pragma unroll
  for (int h = 0; h < H; ++h) den[h] = 0.f;
  float acc[4] = {0.f, 0.f, 0.f, 0.f};

  for (int base = 0; base < deg; base += 64){
    int j = base + lane;
    float t[H]; int sidx = 0;
    if (j < deg){
      sidx = csr_src[beg + j];
      float ev[H];
      if (H == 2){
        float2 e2 = *(const float2*)(es + sidx * 2);
        ev[0] = e2.x; ev[1] = e2.y;
      } else ev[0] = es[sidx];
#pragma unroll
      for (int h = 0; h < H; ++h){
        float e = ev[h] + edn[h];
        e = e > 0.f ? e : e * NEG_SLOPE;
        e = fminf(e, 80.f);
        t[h] = __expf(e);
        den[h] += t[h];
      }
    } else {
#pragma unroll
      for (int h = 0; h < H; ++h) t[h] = 0.f;
    }
    int cnt = deg - base; if (cnt > 64) cnt = 64;

    for (int i = 0; i < cnt; i += EPW){
      int sl = i + grp;                       // edge slot for this lane (<64)
      int sj = __shfl(sidx, sl);              // t==0 masks any overrun slot
      float tf;
      if (H == 2){
        float t0 = __shfl(t[0], sl);
        float t1 = __shfl(t[1], sl);
        tf = hd ? t1 : t0;
      } else {
        tf = __shfl(t[0], sl);
      }
      const ushort* hr = Hb + (size_t)sj * HC + c0;
      uint2 v = *(const uint2*)hr;
      acc[0] = fmaf(tf, bf2f(v.x & 0xffffu), acc[0]);
      acc[1] = fmaf(tf, bf2f(v.x >> 16),     acc[1]);
      acc[2] = fmaf(tf, bf2f(v.y & 0xffffu), acc[2]);
      acc[3] = fmaf(tf, bf2f(v.y >> 16),     acc[3]);
    }
  }

  // reduce denominators across the wave
  float sinv[H];
#pragma unroll
  for (int h = 0; h < H; ++h){
    float v = den[h];
#pragma unroll
    for (int off = 32; off >= 1; off >>= 1) v += __shfl_xor(v, off);
    sinv[h] = 1.f / v;
  }

  // reduce partial channel sums across edge-slot groups
#pragma unroll
  for (int off = LPE; off < 64; off <<= 1){
#pragma unroll
    for (int k = 0; k < 4; ++k) acc[k] += __shfl_xor(acc[k], off);
  }

  if (grp == 0){
    float4 bv = *(const float4*)(b + c0);
    float si = sinv[hd];
    float4 o;
    o.x = fmaf(acc[0], si, bv.x); o.x = o.x > 0.f ? o.x : 0.f;
    o.y = fmaf(acc[1], si, bv.y); o.y = o.y > 0.f ? o.y : 0.f;
    o.z = fmaf(acc[2], si, bv.z); o.z = o.z > 0.f ? o.z : 0.f;
    o.w = fmaf(acc[3], si, bv.w); o.w = o.w > 0.f ? o.w : 0.f;
    *(float4*)(outp + (size_t)n * HC + c0) = o;
  }
}

// ---------------- pooling + FC ----------------

__global__ __launch_bounds__(256) void pool_k(const float* __restrict__ f,
                       const int* __restrict__ batch,
                       float* __restrict__ pooled, float* __restrict__ cnt, int N){
  __shared__ float sp[64 * 16];
  __shared__ float sc[64];
  const int t = threadIdx.x;
  for (int i = t; i < 64 * 16; i += 256) sp[i] = 0.f;
  for (int i = t; i < 64; i += 256) sc[i] = 0.f;
  __syncthreads();
  const int per = (N + gridDim.x - 1) / gridDim.x;
  const int n0 = blockIdx.x * per;
  int n1 = n0 + per; if (n1 > N) n1 = N;
  const int nloc = t >> 4, c = t & 15;
  for (int n = n0 + nloc; n < n1; n += 16){
    int g = batch[n];
    atomicAdd(&sp[g * 16 + c], f[(size_t)n * 16 + c]);
    if (c == 0) atomicAdd(&sc[g], 1.f);
  }
  __syncthreads();
  for (int i = t; i < 64 * 16; i += 256) if (sp[i] != 0.f) atomicAdd(&pooled[i], sp[i]);
  for (int i = t; i < 64; i += 256)      if (sc[i] != 0.f) atomicAdd(&cnt[i], sc[i]);
}

__global__ void final_fc_k(const float* __restrict__ pooled, const float* __restrict__ cnt,
                           const float* __restrict__ fcW, const float* __restrict__ fcb,
                           float* __restrict__ outp){
  int g = threadIdx.x;
  if (g >= 64) return;
  float c = cnt[g]; c = c > 1.f ? c : 1.f;
  float inv = 1.0f / c;
  float acc = fcb[0];
  for (int i = 0; i < 16; ++i) acc = fmaf(pooled[g * 16 + i] * inv, fcW[i], acc);
  outp[g] = 1.0f / (1.0f + expf(-acc));
}

// ---------------- driver ----------------

extern "C" void kernel_launch(void* const* d_in, const int* in_sizes, int n_in,
                              void* d_out, int out_size, void* d_ws, size_t ws_size,
                              hipStream_t stream) {
  const float* x    = (const float*)d_in[0];
  const int*  ei    = (const int*)d_in[1];
  const int*  batch = (const int*)d_in[2];

  const int N = in_sizes[0] / 128;
  const int E = in_sizes[1] / 2;

  const int* src = ei;
  const int* dst = ei + E;

  const float* W_[5];  const float* as_[5]; const float* ad_[5]; const float* b_[5];
  for (int l = 0; l < 5; ++l) {
    W_[l]  = (const float*)d_in[3 + 4 * l + 0];
    as_[l] = (const float*)d_in[3 + 4 * l + 1];
    ad_[l] = (const float*)d_in[3 + 4 * l + 2];
    b_[l]  = (const float*)d_in[3 + 4 * l + 3];
  }
  const float* fcW = (const float*)d_in[23];
  const float* fcb = (const float*)d_in[24];
  float* outp = (float*)d_out;

  // workspace layout
  float*    f_buf  = (float*)d_ws;                       // N*128 fp32 (layer output)
  ushort*   Hb     = (ushort*)(f_buf + (size_t)N * 128); // N*128 bf16 payload
  float*    es     = (float*)(Hb + (size_t)N * 128);     // N*2
  float*    ed     = es + (size_t)N * 2;                 // N*2
  float*    pooled = ed + (size_t)N * 2;                 // 64*16
  float*    cnt    = pooled + 64 * 16;                   // 64
  int*      count  = (int*)(cnt + 64);                   // N
  int*      row_off= count + N;                          // N+1
  int*      cursor = row_off + N + 1;                    // N
  int*      csr_src= cursor + N;                         // E+N
  int*      bcount = csr_src + E + N;                    // 128
  int*      bbase  = bcount + 128;                       // 128
  int*      bcur   = bbase + 128;                        // 128
  unsigned* packed = (unsigned*)(bcur + 128);            // E

  const int K    = (N + BK - 1) / BK;                    // dst buckets
  const int nch  = cdiv_l(E, EPB);                       // edge chunks
  const int g8   = 8 * ((K + 7) / 8) * BPB;              // phase-2 grid

  // ---- build CSR by destination (bucket-partitioned; reused by all 5 layers) ----
  hipMemsetAsync(bcount, 0, 128 * 4, stream);
  hipMemsetAsync(count, 0, (size_t)N * 4, stream);
  bucket_hist_k<<<nch, TPB, 0, stream>>>(dst, bcount, E);
  bucket_scan_k<<<1, 128, 0, stream>>>(bcount, bbase, bcur, K);
  partition_k<<<nch, TPB, 0, stream>>>(src, dst, bcur, packed, E);
  nodehist_k<<<g8, TPB, 0, stream>>>(packed, bbase, bcur, count, K);
  scan_k<<<1, SCAN_T, 0, stream>>>(count, row_off, N);
  cursor_k<<<cdiv_l(N, TPB), TPB, 0, stream>>>(row_off, cursor, csr_src, N);
  bscatter_k<<<g8, TPB, 0, stream>>>(packed, bbase, bcur, cursor, csr_src, K);

  const int gb = cdiv_l(N, 4);

  // layer 1: Fin=128, H=1, C=32
  gemm2_k<128,32,32><<<cdiv_l(N, 1024/32), 256, 0, stream>>>(x, W_[0], as_[0], ad_[0], es, ed, Hb, N);
  agg_k<1,32><<<gb, 256, 0, stream>>>(csr_src, row_off, es, ed, Hb, b_[0], f_buf, N);
  // layer 2: Fin=32, H=2, C=32
  gemm2_k<32,64,32><<<cdiv_l(N, 1024/64), 256, 0, stream>>>(f_buf, W_[1], as_[1], ad_[1], es, ed, Hb, N);
  agg_k<2,32><<<gb, 256, 0, stream>>>(csr_src, row_off, es, ed, Hb, b_[1], f_buf, N);
  // layer 3: Fin=64, H=2, C=64
  gemm2_k<64,128,64><<<cdiv_l(N, 1024/128), 256, 0, stream>>>(f_buf, W_[2], as_[2], ad_[2], es, ed, Hb, N);
  agg_k<2,64><<<gb, 256, 0, stream>>>(csr_src, row_off, es, ed, Hb, b_[2], f_buf, N);
  // layer 4: Fin=128, H=2, C=32
  gemm2_k<128,64,32><<<cdiv_l(N, 1024/64), 256, 0, stream>>>(f_buf, W_[3], as_[3], ad_[3], es, ed, Hb, N);
  agg_k<2,32><<<gb, 256, 0, stream>>>(csr_src, row_off, es, ed, Hb, b_[3], f_buf, N);
  // layer 5: Fin=64, H=2, C=8
  gemm2_k<64,16,8><<<cdiv_l(N, 1024/16), 256, 0, stream>>>(f_buf, W_[4], as_[4], ad_[4], es, ed, Hb, N);
  agg_k<2,8><<<gb, 256, 0, stream>>>(csr_src, row_off, es, ed, Hb, b_[4], f_buf, N);

  // global mean pool (G=64) + FC + sigmoid
  hipMemsetAsync(pooled, 0, (64 * 16 + 64) * 4, stream);
  pool_k<<<64, 256, 0, stream>>>(f_buf, batch, pooled, cnt, N);
  final_fc_k<<<1, 64, 0, stream>>>(pooled, cnt, fcW, fcb, outp);
}

// Round 12
// 462.495 us; speedup vs baseline: 1.2939x; 1.1685x over previous
//
#include <hip/hip_runtime.h>
#include <math.h>

#define TPB 256
#define NEG_SLOPE 0.2f
#define EPB 2048          // edges per block-chunk in streaming CSR kernels
#define BK 512            // nodes per bucket (dst>>9)
#define BPB 8             // blocks per bucket in phase-2 kernels
#define SBN 256           // blocks in multi-block scan

static inline int cdiv_l(long a, int b){ return (int)((a + b - 1) / b); }

__device__ __forceinline__ ushort f2bf(float f){
  unsigned u = __float_as_uint(f);
  unsigned r = u + 0x7fffu + ((u >> 16) & 1u);   // RNE
  return (ushort)(r >> 16);
}
__device__ __forceinline__ float bf2f(unsigned hi16){ return __uint_as_float(hi16 << 16); }

// ---------------- GEMM + fused attention dots + bf16 payload write ----------------
template<int Fin, int HC, int C>
__global__ __launch_bounds__(256) void gemm2_k(const float* __restrict__ X,
        const float* __restrict__ W, const float* __restrict__ as_,
        const float* __restrict__ ad_, float* __restrict__ es, float* __restrict__ ed,
        ushort* __restrict__ Hb, int N){
  constexpr int TPN = HC / 4;         // threads per node
  constexpr int NPB = 256 / TPN;      // nodes per block
  constexpr int H   = HC / C;
  constexpr int RG  = C / 4;          // lanes per (node, head)
  __shared__ float Wl[Fin * HC];
  for (int i = threadIdx.x; i < Fin * HC; i += 256) Wl[i] = W[i];
  __syncthreads();
  const int t  = threadIdx.x;
  const int n  = blockIdx.x * NPB + t / TPN;
  const int jt = (t % TPN) * 4;
  if (n >= N) return;
  const float* xr = X + (size_t)n * Fin;
  float acc[4] = {0.f, 0.f, 0.f, 0.f};
  for (int k = 0; k < Fin; k += 4){
    float4 xv = *(const float4*)(xr + k);
#pragma unroll
    for (int kk = 0; kk < 4; ++kk){
      float xs = (&xv.x)[kk];
#pragma unroll
      for (int j = 0; j < 4; ++j)
        acc[j] = fmaf(xs, Wl[(k + kk) * HC + jt + j], acc[j]);
    }
  }
  ushort4 hb;
  hb.x = f2bf(acc[0]); hb.y = f2bf(acc[1]); hb.z = f2bf(acc[2]); hb.w = f2bf(acc[3]);
  *(ushort4*)(Hb + (size_t)n * HC + jt) = hb;
  const int head = jt / C, col = jt % C;
  float ps = 0.f, pd = 0.f;
#pragma unroll
  for (int j = 0; j < 4; ++j){
    ps = fmaf(acc[j], as_[head * C + col + j], ps);
    pd = fmaf(acc[j], ad_[head * C + col + j], pd);
  }
#pragma unroll
  for (int off = RG >> 1; off >= 1; off >>= 1){
    ps += __shfl_xor(ps, off);
    pd += __shfl_xor(pd, off);
  }
  if ((t % RG) == 0){
    es[n * H + head] = ps;
    ed[n * H + head] = pd;
  }
}

// ---------------- CSR build: two-phase bucket partition ----------------

__global__ __launch_bounds__(256) void bucket_hist_k(const int* __restrict__ dst,
                        int* __restrict__ bcount, int E){
  __shared__ int lh[128];
  const int t = threadIdx.x;
  for (int i = t; i < 128; i += TPB) lh[i] = 0;
  __syncthreads();
  const int c0 = blockIdx.x * EPB;
  int i1 = c0 + EPB; if (i1 > E) i1 = E;
  for (int i = c0 + t; i < i1; i += TPB)
    atomicAdd(&lh[dst[i] >> 9], 1);
  __syncthreads();
  for (int i = t; i < 128; i += TPB)
    if (lh[i]) atomicAdd(&bcount[i], lh[i]);
}

__global__ void bucket_scan_k(const int* __restrict__ bcount,
                              int* __restrict__ bbase, int* __restrict__ bcur, int K){
  __shared__ int v[128];
  const int t = threadIdx.x;     // 128 threads
  int orig = (t < K) ? bcount[t] : 0;
  v[t] = orig; __syncthreads();
  for (int off = 1; off < 128; off <<= 1){
    int y = (t >= off) ? v[t - off] : 0;
    __syncthreads();
    v[t] += y;
    __syncthreads();
  }
  int excl = v[t] - orig;
  if (t < K){ bbase[t] = excl; bcur[t] = excl; }
}

__global__ __launch_bounds__(256) void partition_k(const int* __restrict__ src,
                        const int* __restrict__ dst,
                        int* __restrict__ bcur, unsigned* __restrict__ packed, int E){
  __shared__ int lh[128];     // per-bucket local count, then local rank cursor
  __shared__ int lofs[128];   // global base reserved for this block
  const int t = threadIdx.x;
  for (int i = t; i < 128; i += TPB) lh[i] = 0;
  __syncthreads();
  const int c0 = blockIdx.x * EPB;
  int i1 = c0 + EPB; if (i1 > E) i1 = E;
  for (int i = c0 + t; i < i1; i += TPB)
    atomicAdd(&lh[dst[i] >> 9], 1);
  __syncthreads();
  if (t < 128){
    lofs[t] = lh[t] ? atomicAdd(&bcur[t], lh[t]) : 0;
    lh[t] = 0;
  }
  __syncthreads();
  for (int i = c0 + t; i < i1; i += TPB){
    int d = dst[i], k = d >> 9;
    int r = atomicAdd(&lh[k], 1);                       // LDS rank
    packed[lofs[k] + r] = ((unsigned)src[i] << 9) | (unsigned)(d & 511);
  }
}

// Phase 2: per bucket (8 blocks, same XCD via blockIdx&7)

__device__ __forceinline__ bool bucket_range(const int* bbase, const int* bcur,
        int K, int& k, int& i0, int& i1, int& nb){
  const int slice = blockIdx.x & 7;
  const int q = blockIdx.x >> 3;
  const int kk = q / BPB, c = q % BPB;
  k = kk * 8 + slice;
  if (k >= K) return false;
  const int b0 = bbase[k];
  const int sz = bcur[k] - b0;
  const int per = (sz + BPB - 1) / BPB;
  i0 = b0 + c * per;
  i1 = b0 + sz; if (i0 + per < i1) i1 = i0 + per;
  nb = k << 9;
  return i0 < i1;
}

__global__ __launch_bounds__(256) void nodehist_k(const unsigned* __restrict__ packed,
                        const int* __restrict__ bbase, const int* __restrict__ bcur,
                        int* __restrict__ count, int K){
  int k, i0, i1, nb;
  if (!bucket_range(bbase, bcur, K, k, i0, i1, nb)) return;
  for (int i = i0 + threadIdx.x; i < i1; i += TPB){
    unsigned pk = packed[i];
    atomicAdd(&count[nb + (int)(pk & 511u)], 1);
  }
}

// ---------------- multi-block scan of count[i]+1 -> row_off ----------------

__global__ __launch_bounds__(256) void partial_k(const int* __restrict__ count,
                        int* __restrict__ psum, int N){
  const int per = (N + gridDim.x - 1) / gridDim.x;
  const int b0 = blockIdx.x * per;
  int b1 = b0 + per; if (b1 > N) b1 = N;
  int s = 0;
  for (int i = b0 + threadIdx.x; i < b1; i += 256) s += count[i] + 1;
#pragma unroll
  for (int off = 32; off >= 1; off >>= 1) s += __shfl_xor(s, off);
  __shared__ int ws[4];
  if ((threadIdx.x & 63) == 0) ws[threadIdx.x >> 6] = s;
  __syncthreads();
  if (threadIdx.x == 0) psum[blockIdx.x] = ws[0] + ws[1] + ws[2] + ws[3];
}

__global__ void pscan_k(int* __restrict__ psum, int n){
  __shared__ int v[SBN];
  const int t = threadIdx.x;
  int orig = (t < n) ? psum[t] : 0;
  v[t] = orig; __syncthreads();
  for (int off = 1; off < SBN; off <<= 1){
    int y = (t >= off) ? v[t - off] : 0;
    __syncthreads();
    v[t] += y;
    __syncthreads();
  }
  if (t < n) psum[t] = v[t] - orig;   // exclusive
}

__global__ __launch_bounds__(256) void rowoff_k(const int* __restrict__ count,
                        const int* __restrict__ psum, int* __restrict__ row_off,
                        int N, int total){
  const int per = (N + gridDim.x - 1) / gridDim.x;
  const int b0 = blockIdx.x * per;
  int b1 = b0 + per; if (b1 > N) b1 = N;
  int base = psum[blockIdx.x];
  __shared__ int tile[256];
  const int t = threadIdx.x;
  for (int start = b0; start < b1; start += 256){
    int i = start + t;
    int v = (i < b1) ? count[i] + 1 : 0;
    tile[t] = v; __syncthreads();
    for (int off = 1; off < 256; off <<= 1){
      int y = (t >= off) ? tile[t - off] : 0;
      __syncthreads();
      tile[t] += y;
      __syncthreads();
    }
    if (i < b1) row_off[i] = base + tile[t] - v;
    base += tile[255];
    __syncthreads();
  }
  if (blockIdx.x == 0 && t == 0) row_off[N] = total;
}

__global__ void cursor_k(const int* __restrict__ row_off, int* __restrict__ cursor,
                         int* __restrict__ csr_src, int N){
  int i = blockIdx.x * TPB + threadIdx.x;
  if (i >= N) return;
  int r = row_off[i];
  csr_src[r] = i;          // self-loop occupies first slot
  cursor[i] = r + 1;
}

__global__ __launch_bounds__(256) void bscatter_k(const unsigned* __restrict__ packed,
                        const int* __restrict__ bbase, const int* __restrict__ bcur,
                        int* __restrict__ cursor, int* __restrict__ csr_src, int K){
  int k, i0, i1, nb;
  if (!bucket_range(bbase, bcur, K, k, i0, i1, nb)) return;
  for (int i = i0 + threadIdx.x; i < i1; i += TPB){
    unsigned pk = packed[i];
    int d = nb + (int)(pk & 511u);
    int p = atomicAdd(&cursor[d], 1);
    csr_src[p] = (int)(pk >> 9);
  }
}

// ---------------- fused single-pass softmax + aggregate + bias + relu ----------------

template<int H, int C>
__global__ __launch_bounds__(256) void agg_k(const int* __restrict__ csr_src,
        const int* __restrict__ row_off,
        const float* __restrict__ es, const float* __restrict__ ed,
        const ushort* __restrict__ Hb, const float* __restrict__ b,
        float* __restrict__ outp, int N){
  constexpr int HC  = H * C;
  constexpr int LPE = HC / 4;         // lanes per edge
  constexpr int EPW = 64 / LPE;       // edges per wave-iteration
  const int lane = threadIdx.x & 63;
  const int wv   = threadIdx.x >> 6;
  const int n = blockIdx.x * 4 + wv;
  if (n >= N) return;
  const int beg = row_off[n];
  const int deg = row_off[n + 1] - beg;

  const int grp  = lane / LPE;        // which edge slot this lane serves
  const int cpos = lane % LPE;        // which 4-channel group
  const int c0   = cpos * 4;
  const int hd   = c0 / C;            // head of this lane's channels (C%4==0)

  float edn[H];
#pragma unroll
  for (int h = 0; h < H; ++h) edn[h] = ed[n * H + h];

  float den[H];
#pragma unroll
  for (int h = 0; h < H; ++h) den[h] = 0.f;
  float acc[4] = {0.f, 0.f, 0.f, 0.f};

  for (int base = 0; base < deg; base += 64){
    int j = base + lane;
    float t[H]; int sidx = 0;
    if (j < deg){
      sidx = csr_src[beg + j];
      float ev[H];
      if (H == 2){
        float2 e2 = *(const float2*)(es + sidx * 2);
        ev[0] = e2.x; ev[1] = e2.y;
      } else ev[0] = es[sidx];
#pragma unroll
      for (int h = 0; h < H; ++h){
        float e = ev[h] + edn[h];
        e = e > 0.f ? e : e * NEG_SLOPE;
        e = fminf(e, 80.f);
        t[h] = __expf(e);
        den[h] += t[h];
      }
    } else {
#pragma unroll
      for (int h = 0; h < H; ++h) t[h] = 0.f;
    }
    int cnt = deg - base; if (cnt > 64) cnt = 64;

    for (int i = 0; i < cnt; i += EPW){
      int sl = i + grp;                       // edge slot for this lane (<64)
      int sj = __shfl(sidx, sl);              // t==0 masks any overrun slot
      float tf;
      if (H == 2){
        float t0 = __shfl(t[0], sl);
        float t1 = __shfl(t[1], sl);
        tf = hd ? t1 : t0;
      } else {
        tf = __shfl(t[0], sl);
      }
      const ushort* hr = Hb + (size_t)sj * HC + c0;
      uint2 v = *(const uint2*)hr;
      acc[0] = fmaf(tf, bf2f(v.x & 0xffffu), acc[0]);
      acc[1] = fmaf(tf, bf2f(v.x >> 16),     acc[1]);
      acc[2] = fmaf(tf, bf2f(v.y & 0xffffu), acc[2]);
      acc[3] = fmaf(tf, bf2f(v.y >> 16),     acc[3]);
    }
  }

  // reduce denominators across the wave
  float sinv[H];
#pragma unroll
  for (int h = 0; h < H; ++h){
    float v = den[h];
#pragma unroll
    for (int off = 32; off >= 1; off >>= 1) v += __shfl_xor(v, off);
    sinv[h] = 1.f / v;
  }

  // reduce partial channel sums across edge-slot groups
#pragma unroll
  for (int off = LPE; off < 64; off <<= 1){
#pragma unroll
    for (int k = 0; k < 4; ++k) acc[k] += __shfl_xor(acc[k], off);
  }

  if (grp == 0){
    float4 bv = *(const float4*)(b + c0);
    float si = sinv[hd];
    float4 o;
    o.x = fmaf(acc[0], si, bv.x); o.x = o.x > 0.f ? o.x : 0.f;
    o.y = fmaf(acc[1], si, bv.y); o.y = o.y > 0.f ? o.y : 0.f;
    o.z = fmaf(acc[2], si, bv.z); o.z = o.z > 0.f ? o.z : 0.f;
    o.w = fmaf(acc[3], si, bv.w); o.w = o.w > 0.f ? o.w : 0.f;
    *(float4*)(outp + (size_t)n * HC + c0) = o;
  }
}

// ---------------- pooling + FC ----------------

__global__ __launch_bounds__(256) void pool_k(const float* __restrict__ f,
                       const int* __restrict__ batch,
                       float* __restrict__ pooled, float* __restrict__ cnt, int N){
  __shared__ float sp[64 * 16];
  __shared__ float sc[64];
  const int t = threadIdx.x;
  for (int i = t; i < 64 * 16; i += 256) sp[i] = 0.f;
  for (int i = t; i < 64; i += 256) sc[i] = 0.f;
  __syncthreads();
  const int per = (N + gridDim.x - 1) / gridDim.x;
  const int n0 = blockIdx.x * per;
  int n1 = n0 + per; if (n1 > N) n1 = N;
  const int nloc = t >> 4, c = t & 15;
  for (int n = n0 + nloc; n < n1; n += 16){
    int g = batch[n];
    atomicAdd(&sp[g * 16 + c], f[(size_t)n * 16 + c]);
    if (c == 0) atomicAdd(&sc[g], 1.f);
  }
  __syncthreads();
  for (int i = t; i < 64 * 16; i += 256) if (sp[i] != 0.f) atomicAdd(&pooled[i], sp[i]);
  for (int i = t; i < 64; i += 256)      if (sc[i] != 0.f) atomicAdd(&cnt[i], sc[i]);
}

__global__ void final_fc_k(const float* __restrict__ pooled, const float* __restrict__ cnt,
                           const float* __restrict__ fcW, const float* __restrict__ fcb,
                           float* __restrict__ outp){
  int g = threadIdx.x;
  if (g >= 64) return;
  float c = cnt[g]; c = c > 1.f ? c : 1.f;
  float inv = 1.0f / c;
  float acc = fcb[0];
  for (int i = 0; i < 16; ++i) acc = fmaf(pooled[g * 16 + i] * inv, fcW[i], acc);
  outp[g] = 1.0f / (1.0f + expf(-acc));
}

// ---------------- driver ----------------

extern "C" void kernel_launch(void* const* d_in, const int* in_sizes, int n_in,
                              void* d_out, int out_size, void* d_ws, size_t ws_size,
                              hipStream_t stream) {
  const float* x    = (const float*)d_in[0];
  const int*  ei    = (const int*)d_in[1];
  const int*  batch = (const int*)d_in[2];

  const int N = in_sizes[0] / 128;
  const int E = in_sizes[1] / 2;

  const int* src = ei;
  const int* dst = ei + E;

  const float* W_[5];  const float* as_[5]; const float* ad_[5]; const float* b_[5];
  for (int l = 0; l < 5; ++l) {
    W_[l]  = (const float*)d_in[3 + 4 * l + 0];
    as_[l] = (const float*)d_in[3 + 4 * l + 1];
    ad_[l] = (const float*)d_in[3 + 4 * l + 2];
    b_[l]  = (const float*)d_in[3 + 4 * l + 3];
  }
  const float* fcW = (const float*)d_in[23];
  const float* fcb = (const float*)d_in[24];
  float* outp = (float*)d_out;

  // workspace layout
  float*    f_buf  = (float*)d_ws;                       // N*128 fp32 (layer output)
  ushort*   Hb     = (ushort*)(f_buf + (size_t)N * 128); // N*128 bf16 payload
  float*    es     = (float*)(Hb + (size_t)N * 128);     // N*2
  float*    ed     = es + (size_t)N * 2;                 // N*2
  float*    pooled = ed + (size_t)N * 2;                 // 64*16
  float*    cnt    = pooled + 64 * 16;                   // 64
  int*      count  = (int*)(cnt + 64);                   // N
  int*      row_off= count + N;                          // N+1
  int*      cursor = row_off + N + 1;                    // N
  int*      csr_src= cursor + N;                         // E+N
  int*      bcount = csr_src + E + N;                    // 128
  int*      bbase  = bcount + 128;                       // 128
  int*      bcur   = bbase + 128;                        // 128
  int*      psum   = bcur + 128;                         // SBN
  unsigned* packed = (unsigned*)(psum + SBN);            // E

  const int K    = (N + BK - 1) / BK;                    // dst buckets
  const int nch  = cdiv_l(E, EPB);                       // edge chunks
  const int g8   = 8 * ((K + 7) / 8) * BPB;              // phase-2 grid

  // ---- build CSR by destination (bucket-partitioned; reused by all 5 layers) ----
  hipMemsetAsync(bcount, 0, 128 * 4, stream);
  hipMemsetAsync(count, 0, (size_t)N * 4, stream);
  bucket_hist_k<<<nch, TPB, 0, stream>>>(dst, bcount, E);
  bucket_scan_k<<<1, 128, 0, stream>>>(bcount, bbase, bcur, K);
  partition_k<<<nch, TPB, 0, stream>>>(src, dst, bcur, packed, E);
  nodehist_k<<<g8, TPB, 0, stream>>>(packed, bbase, bcur, count, K);
  partial_k<<<SBN, 256, 0, stream>>>(count, psum, N);
  pscan_k<<<1, SBN, 0, stream>>>(psum, SBN);
  rowoff_k<<<SBN, 256, 0, stream>>>(count, psum, row_off, N, E + N);
  cursor_k<<<cdiv_l(N, TPB), TPB, 0, stream>>>(row_off, cursor, csr_src, N);
  bscatter_k<<<g8, TPB, 0, stream>>>(packed, bbase, bcur, cursor, csr_src, K);

  const int gb = cdiv_l(N, 4);

  // layer 1: Fin=128, H=1, C=32
  gemm2_k<128,32,32><<<cdiv_l(N, 1024/32), 256, 0, stream>>>(x, W_[0], as_[0], ad_[0], es, ed, Hb, N);
  agg_k<1,32><<<gb, 256, 0, stream>>>(csr_src, row_off, es, ed, Hb, b_[0], f_buf, N);
  // layer 2: Fin=32, H=2, C=32
  gemm2_k<32,64,32><<<cdiv_l(N, 1024/64), 256, 0, stream>>>(f_buf, W_[1], as_[1], ad_[1], es, ed, Hb, N);
  agg_k<2,32><<<gb, 256, 0, stream>>>(csr_src, row_off, es, ed, Hb, b_[1], f_buf, N);
  // layer 3: Fin=64, H=2, C=64
  gemm2_k<64,128,64><<<cdiv_l(N, 1024/128), 256, 0, stream>>>(f_buf, W_[2], as_[2], ad_[2], es, ed, Hb, N);
  agg_k<2,64><<<gb, 256, 0, stream>>>(csr_src, row_off, es, ed, Hb, b_[2], f_buf, N);
  // layer 4: Fin=128, H=2, C=32
  gemm2_k<128,64,32><<<cdiv_l(N, 1024/64), 256, 0, stream>>>(f_buf, W_[3], as_[3], ad_[3], es, ed, Hb, N);
  agg_k<2,32><<<gb, 256, 0, stream>>>(csr_src, row_off, es, ed, Hb, b_[3], f_buf, N);
  // layer 5: Fin=64, H=2, C=8
  gemm2_k<64,16,8><<<cdiv_l(N, 1024/16), 256, 0, stream>>>(f_buf, W_[4], as_[4], ad_[4], es, ed, Hb, N);
  agg_k<2,8><<<gb, 256, 0, stream>>>(csr_src, row_off, es, ed, Hb, b_[4], f_buf, N);

  // global mean pool (G=64) + FC + sigmoid
  hipMemsetAsync(pooled, 0, (64 * 16 + 64) * 4, stream);
  pool_k<<<64, 256, 0, stream>>>(f_buf, batch, pooled, cnt, N);
  final_fc_k<<<1, 64, 0, stream>>>(pooled, cnt, fcW, fcb, outp);
}

// Round 13
// 437.073 us; speedup vs baseline: 1.3692x; 1.0582x over previous
//
#include <hip/hip_runtime.h>
#include <math.h>

#define TPB 256
#define NEG_SLOPE 0.2f
#define EPB 2048          // edges per block-chunk in streaming CSR kernels
#define BK 512            // nodes per bucket (dst>>9)
#define BPB 8             // blocks per bucket in phase-2 kernels
#define SBN 256           // blocks in multi-block scan

static inline int cdiv_l(long a, int b){ return (int)((a + b - 1) / b); }

typedef float v2f __attribute__((ext_vector_type(2)));

// ---------------- GEMM + fused attention dots + fp8 payload write ----------------
template<int Fin, int HC, int C>
__global__ __launch_bounds__(256) void gemm2_k(const float* __restrict__ X,
        const float* __restrict__ W, const float* __restrict__ as_,
        const float* __restrict__ ad_, float* __restrict__ es, float* __restrict__ ed,
        unsigned char* __restrict__ Hb, int N){
  constexpr int TPN = HC / 4;         // threads per node
  constexpr int NPB = 256 / TPN;      // nodes per block
  constexpr int H   = HC / C;
  constexpr int RG  = C / 4;          // lanes per (node, head)
  __shared__ float Wl[Fin * HC];
  for (int i = threadIdx.x; i < Fin * HC; i += 256) Wl[i] = W[i];
  __syncthreads();
  const int t  = threadIdx.x;
  const int n  = blockIdx.x * NPB + t / TPN;
  const int jt = (t % TPN) * 4;
  if (n >= N) return;
  const float* xr = X + (size_t)n * Fin;
  float acc[4] = {0.f, 0.f, 0.f, 0.f};
  for (int k = 0; k < Fin; k += 4){
    float4 xv = *(const float4*)(xr + k);
#pragma unroll
    for (int kk = 0; kk < 4; ++kk){
      float xs = (&xv.x)[kk];
#pragma unroll
      for (int j = 0; j < 4; ++j)
        acc[j] = fmaf(xs, Wl[(k + kk) * HC + jt + j], acc[j]);
    }
  }
  // fp8 e4m3 payload write (4B per thread, coalesced), HW packed convert
  int pk8 = __builtin_amdgcn_cvt_pk_fp8_f32(acc[0], acc[1], 0, false);
  pk8     = __builtin_amdgcn_cvt_pk_fp8_f32(acc[2], acc[3], pk8, true);
  *(int*)(Hb + (size_t)n * HC + jt) = pk8;
  // fused attention dots (from unquantized fp32 accumulators)
  const int head = jt / C, col = jt % C;
  float ps = 0.f, pd = 0.f;
#pragma unroll
  for (int j = 0; j < 4; ++j){
    ps = fmaf(acc[j], as_[head * C + col + j], ps);
    pd = fmaf(acc[j], ad_[head * C + col + j], pd);
  }
#pragma unroll
  for (int off = RG >> 1; off >= 1; off >>= 1){
    ps += __shfl_xor(ps, off);
    pd += __shfl_xor(pd, off);
  }
  if ((t % RG) == 0){
    es[n * H + head] = ps;
    ed[n * H + head] = pd;
  }
}

// ---------------- CSR build: two-phase bucket partition ----------------

__global__ __launch_bounds__(256) void bucket_hist_k(const int* __restrict__ dst,
                        int* __restrict__ bcount, int E){
  __shared__ int lh[128];
  const int t = threadIdx.x;
  for (int i = t; i < 128; i += TPB) lh[i] = 0;
  __syncthreads();
  const int c0 = blockIdx.x * EPB;
  int i1 = c0 + EPB; if (i1 > E) i1 = E;
  for (int i = c0 + t; i < i1; i += TPB)
    atomicAdd(&lh[dst[i] >> 9], 1);
  __syncthreads();
  for (int i = t; i < 128; i += TPB)
    if (lh[i]) atomicAdd(&bcount[i], lh[i]);
}

__global__ void bucket_scan_k(const int* __restrict__ bcount,
                              int* __restrict__ bbase, int* __restrict__ bcur, int K){
  __shared__ int v[128];
  const int t = threadIdx.x;     // 128 threads
  int orig = (t < K) ? bcount[t] : 0;
  v[t] = orig; __syncthreads();
  for (int off = 1; off < 128; off <<= 1){
    int y = (t >= off) ? v[t - off] : 0;
    __syncthreads();
    v[t] += y;
    __syncthreads();
  }
  int excl = v[t] - orig;
  if (t < K){ bbase[t] = excl; bcur[t] = excl; }
}

__global__ __launch_bounds__(256) void partition_k(const int* __restrict__ src,
                        const int* __restrict__ dst,
                        int* __restrict__ bcur, unsigned* __restrict__ packed, int E){
  __shared__ int lh[128];     // per-bucket local count, then local rank cursor
  __shared__ int lofs[128];   // global base reserved for this block
  const int t = threadIdx.x;
  for (int i = t; i < 128; i += TPB) lh[i] = 0;
  __syncthreads();
  const int c0 = blockIdx.x * EPB;
  int i1 = c0 + EPB; if (i1 > E) i1 = E;
  for (int i = c0 + t; i < i1; i += TPB)
    atomicAdd(&lh[dst[i] >> 9], 1);
  __syncthreads();
  if (t < 128){
    lofs[t] = lh[t] ? atomicAdd(&bcur[t], lh[t]) : 0;
    lh[t] = 0;
  }
  __syncthreads();
  for (int i = c0 + t; i < i1; i += TPB){
    int d = dst[i], k = d >> 9;
    int r = atomicAdd(&lh[k], 1);                       // LDS rank
    packed[lofs[k] + r] = ((unsigned)src[i] << 9) | (unsigned)(d & 511);
  }
}

// Phase 2: per bucket (8 blocks, same XCD via blockIdx&7)

__device__ __forceinline__ bool bucket_range(const int* bbase, const int* bcur,
        int K, int& k, int& i0, int& i1, int& nb){
  const int slice = blockIdx.x & 7;
  const int q = blockIdx.x >> 3;
  const int kk = q / BPB, c = q % BPB;
  k = kk * 8 + slice;
  if (k >= K) return false;
  const int b0 = bbase[k];
  const int sz = bcur[k] - b0;
  const int per = (sz + BPB - 1) / BPB;
  i0 = b0 + c * per;
  i1 = b0 + sz; if (i0 + per < i1) i1 = i0 + per;
  nb = k << 9;
  return i0 < i1;
}

__global__ __launch_bounds__(256) void nodehist_k(const unsigned* __restrict__ packed,
                        const int* __restrict__ bbase, const int* __restrict__ bcur,
                        int* __restrict__ count, int K){
  int k, i0, i1, nb;
  if (!bucket_range(bbase, bcur, K, k, i0, i1, nb)) return;
  for (int i = i0 + threadIdx.x; i < i1; i += TPB){
    unsigned pk = packed[i];
    atomicAdd(&count[nb + (int)(pk & 511u)], 1);
  }
}

// ---------------- multi-block scan of count[i]+1 -> row_off ----------------

__global__ __launch_bounds__(256) void partial_k(const int* __restrict__ count,
                        int* __restrict__ psum, int N){
  const int per = (N + gridDim.x - 1) / gridDim.x;
  const int b0 = blockIdx.x * per;
  int b1 = b0 + per; if (b1 > N) b1 = N;
  int s = 0;
  for (int i = b0 + threadIdx.x; i < b1; i += 256) s += count[i] + 1;
#pragma unroll
  for (int off = 32; off >= 1; off >>= 1) s += __shfl_xor(s, off);
  __shared__ int ws[4];
  if ((threadIdx.x & 63) == 0) ws[threadIdx.x >> 6] = s;
  __syncthreads();
  if (threadIdx.x == 0) psum[blockIdx.x] = ws[0] + ws[1] + ws[2] + ws[3];
}

__global__ void pscan_k(int* __restrict__ psum, int n){
  __shared__ int v[SBN];
  const int t = threadIdx.x;
  int orig = (t < n) ? psum[t] : 0;
  v[t] = orig; __syncthreads();
  for (int off = 1; off < SBN; off <<= 1){
    int y = (t >= off) ? v[t - off] : 0;
    __syncthreads();
    v[t] += y;
    __syncthreads();
  }
  if (t < n) psum[t] = v[t] - orig;   // exclusive
}

__global__ __launch_bounds__(256) void rowoff_k(const int* __restrict__ count,
                        const int* __restrict__ psum, int* __restrict__ row_off,
                        int N, int total){
  const int per = (N + gridDim.x - 1) / gridDim.x;
  const int b0 = blockIdx.x * per;
  int b1 = b0 + per; if (b1 > N) b1 = N;
  int base = psum[blockIdx.x];
  __shared__ int tile[256];
  const int t = threadIdx.x;
  for (int start = b0; start < b1; start += 256){
    int i = start + t;
    int v = (i < b1) ? count[i] + 1 : 0;
    tile[t] = v; __syncthreads();
    for (int off = 1; off < 256; off <<= 1){
      int y = (t >= off) ? tile[t - off] : 0;
      __syncthreads();
      tile[t] += y;
      __syncthreads();
    }
    if (i < b1) row_off[i] = base + tile[t] - v;
    base += tile[255];
    __syncthreads();
  }
  if (blockIdx.x == 0 && t == 0) row_off[N] = total;
}

__global__ void cursor_k(const int* __restrict__ row_off, int* __restrict__ cursor,
                         int* __restrict__ csr_src, int N){
  int i = blockIdx.x * TPB + threadIdx.x;
  if (i >= N) return;
  int r = row_off[i];
  csr_src[r] = i;          // self-loop occupies first slot
  cursor[i] = r + 1;
}

__global__ __launch_bounds__(256) void bscatter_k(const unsigned* __restrict__ packed,
                        const int* __restrict__ bbase, const int* __restrict__ bcur,
                        int* __restrict__ cursor, int* __restrict__ csr_src, int K){
  int k, i0, i1, nb;
  if (!bucket_range(bbase, bcur, K, k, i0, i1, nb)) return;
  for (int i = i0 + threadIdx.x; i < i1; i += TPB){
    unsigned pk = packed[i];
    int d = nb + (int)(pk & 511u);
    int p = atomicAdd(&cursor[d], 1);
    csr_src[p] = (int)(pk >> 9);
  }
}

// ---------------- fused single-pass softmax + aggregate + bias + relu ----------------
// one wave per destination node; fp8 e4m3 payload (HW cvt), fp32 accumulate.
// t = exp(min(leaky(es+ed),80)) (shift-free softmax); acc += t*h; den += t.
// Each lane owns 8 channels (one dwordx2 of fp8), LPE=HC/8 lanes per edge,
// EPW=64/LPE edges per wave-iteration. Invalid slots carry t=0 -> branch-free.

template<int H, int C>
__global__ __launch_bounds__(256) void agg_k(const int* __restrict__ csr_src,
        const int* __restrict__ row_off,
        const float* __restrict__ es, const float* __restrict__ ed,
        const unsigned char* __restrict__ Hb, const float* __restrict__ b,
        float* __restrict__ outp, int N){
  constexpr int HC  = H * C;
  constexpr int LPE = HC / 8;         // lanes per edge
  constexpr int EPW = 64 / LPE;       // edges per wave-iteration
  const int lane = threadIdx.x & 63;
  const int wv   = threadIdx.x >> 6;
  const int n = blockIdx.x * 4 + wv;
  if (n >= N) return;
  const int beg = row_off[n];
  const int deg = row_off[n + 1] - beg;

  const int grp  = lane / LPE;        // which edge slot this lane serves
  const int cpos = lane % LPE;        // which 8-channel group
  const int c0   = cpos * 8;
  const int hd   = c0 / C;            // head of this lane's channels (8<=C)

  float edn[H];
#pragma unroll
  for (int h = 0; h < H; ++h) edn[h] = ed[n * H + h];

  float den[H];
#pragma unroll
  for (int h = 0; h < H; ++h) den[h] = 0.f;
  float acc[8] = {0.f,0.f,0.f,0.f,0.f,0.f,0.f,0.f};

  for (int base = 0; base < deg; base += 64){
    int j = base + lane;
    float t[H]; int sidx = 0;
    if (j < deg){
      sidx = csr_src[beg + j];
      float ev[H];
      if (H == 2){
        float2 e2 = *(const float2*)(es + sidx * 2);
        ev[0] = e2.x; ev[1] = e2.y;
      } else ev[0] = es[sidx];
#pragma unroll
      for (int h = 0; h < H; ++h){
        float e = ev[h] + edn[h];
        e = e > 0.f ? e : e * NEG_SLOPE;
        e = fminf(e, 80.f);
        t[h] = __expf(e);
        den[h] += t[h];
      }
    } else {
#pragma unroll
      for (int h = 0; h < H; ++h) t[h] = 0.f;
    }
    int cnt = deg - base; if (cnt > 64) cnt = 64;

    for (int i = 0; i < cnt; i += EPW){
      int sl = i + grp;                       // edge slot for this lane (<64)
      int sj = __shfl(sidx, sl);              // t==0 masks any overrun slot
      float tf;
      if (H == 2){
        float t0 = __shfl(t[0], sl);
        float t1 = __shfl(t[1], sl);
        tf = hd ? t1 : t0;
      } else {
        tf = __shfl(t[0], sl);
      }
      const unsigned char* hr = Hb + (size_t)sj * HC + c0;
      uint2 v = *(const uint2*)hr;
      v2f p0 = __builtin_amdgcn_cvt_pk_f32_fp8((int)v.x, false);
      v2f p1 = __builtin_amdgcn_cvt_pk_f32_fp8((int)v.x, true);
      v2f p2 = __builtin_amdgcn_cvt_pk_f32_fp8((int)v.y, false);
      v2f p3 = __builtin_amdgcn_cvt_pk_f32_fp8((int)v.y, true);
      acc[0] = fmaf(tf, p0[0], acc[0]);
      acc[1] = fmaf(tf, p0[1], acc[1]);
      acc[2] = fmaf(tf, p1[0], acc[2]);
      acc[3] = fmaf(tf, p1[1], acc[3]);
      acc[4] = fmaf(tf, p2[0], acc[4]);
      acc[5] = fmaf(tf, p2[1], acc[5]);
      acc[6] = fmaf(tf, p3[0], acc[6]);
      acc[7] = fmaf(tf, p3[1], acc[7]);
    }
  }

  // reduce denominators across the wave
  float sinv[H];
#pragma unroll
  for (int h = 0; h < H; ++h){
    float v = den[h];
#pragma unroll
    for (int off = 32; off >= 1; off >>= 1) v += __shfl_xor(v, off);
    sinv[h] = 1.f / v;
  }

  // reduce partial channel sums across edge-slot groups
#pragma unroll
  for (int off = LPE; off < 64; off <<= 1){
#pragma unroll
    for (int k = 0; k < 8; ++k) acc[k] += __shfl_xor(acc[k], off);
  }

  if (grp == 0){
    float si = sinv[hd];
    float4 b0 = *(const float4*)(b + c0);
    float4 b1 = *(const float4*)(b + c0 + 4);
    float4 o0, o1;
    o0.x = fmaf(acc[0], si, b0.x); o0.x = o0.x > 0.f ? o0.x : 0.f;
    o0.y = fmaf(acc[1], si, b0.y); o0.y = o0.y > 0.f ? o0.y : 0.f;
    o0.z = fmaf(acc[2], si, b0.z); o0.z = o0.z > 0.f ? o0.z : 0.f;
    o0.w = fmaf(acc[3], si, b0.w); o0.w = o0.w > 0.f ? o0.w : 0.f;
    o1.x = fmaf(acc[4], si, b1.x); o1.x = o1.x > 0.f ? o1.x : 0.f;
    o1.y = fmaf(acc[5], si, b1.y); o1.y = o1.y > 0.f ? o1.y : 0.f;
    o1.z = fmaf(acc[6], si, b1.z); o1.z = o1.z > 0.f ? o1.z : 0.f;
    o1.w = fmaf(acc[7], si, b1.w); o1.w = o1.w > 0.f ? o1.w : 0.f;
    *(float4*)(outp + (size_t)n * HC + c0)     = o0;
    *(float4*)(outp + (size_t)n * HC + c0 + 4) = o1;
  }
}

// ---------------- pooling + FC ----------------

__global__ __launch_bounds__(256) void pool_k(const float* __restrict__ f,
                       const int* __restrict__ batch,
                       float* __restrict__ pooled, float* __restrict__ cnt, int N){
  __shared__ float sp[64 * 16];
  __shared__ float sc[64];
  const int t = threadIdx.x;
  for (int i = t; i < 64 * 16; i += 256) sp[i] = 0.f;
  for (int i = t; i < 64; i += 256) sc[i] = 0.f;
  __syncthreads();
  const int per = (N + gridDim.x - 1) / gridDim.x;
  const int n0 = blockIdx.x * per;
  int n1 = n0 + per; if (n1 > N) n1 = N;
  const int nloc = t >> 4, c = t & 15;
  for (int n = n0 + nloc; n < n1; n += 16){
    int g = batch[n];
    atomicAdd(&sp[g * 16 + c], f[(size_t)n * 16 + c]);
    if (c == 0) atomicAdd(&sc[g], 1.f);
  }
  __syncthreads();
  for (int i = t; i < 64 * 16; i += 256) if (sp[i] != 0.f) atomicAdd(&pooled[i], sp[i]);
  for (int i = t; i < 64; i += 256)      if (sc[i] != 0.f) atomicAdd(&cnt[i], sc[i]);
}

__global__ void final_fc_k(const float* __restrict__ pooled, const float* __restrict__ cnt,
                           const float* __restrict__ fcW, const float* __restrict__ fcb,
                           float* __restrict__ outp){
  int g = threadIdx.x;
  if (g >= 64) return;
  float c = cnt[g]; c = c > 1.f ? c : 1.f;
  float inv = 1.0f / c;
  float acc = fcb[0];
  for (int i = 0; i < 16; ++i) acc = fmaf(pooled[g * 16 + i] * inv, fcW[i], acc);
  outp[g] = 1.0f / (1.0f + expf(-acc));
}

// ---------------- driver ----------------

extern "C" void kernel_launch(void* const* d_in, const int* in_sizes, int n_in,
                              void* d_out, int out_size, void* d_ws, size_t ws_size,
                              hipStream_t stream) {
  const float* x    = (const float*)d_in[0];
  const int*  ei    = (const int*)d_in[1];
  const int*  batch = (const int*)d_in[2];

  const int N = in_sizes[0] / 128;
  const int E = in_sizes[1] / 2;

  const int* src = ei;
  const int* dst = ei + E;

  const float* W_[5];  const float* as_[5]; const float* ad_[5]; const float* b_[5];
  for (int l = 0; l < 5; ++l) {
    W_[l]  = (const float*)d_in[3 + 4 * l + 0];
    as_[l] = (const float*)d_in[3 + 4 * l + 1];
    ad_[l] = (const float*)d_in[3 + 4 * l + 2];
    b_[l]  = (const float*)d_in[3 + 4 * l + 3];
  }
  const float* fcW = (const float*)d_in[23];
  const float* fcb = (const float*)d_in[24];
  float* outp = (float*)d_out;

  // workspace layout
  float*         f_buf  = (float*)d_ws;                       // N*128 fp32 (layer output)
  unsigned char* Hb     = (unsigned char*)(f_buf + (size_t)N * 128); // N*128 fp8 payload
  float*         es     = (float*)(Hb + (size_t)N * 128);     // N*2
  float*         ed     = es + (size_t)N * 2;                 // N*2
  float*         pooled = ed + (size_t)N * 2;                 // 64*16
  float*         cnt    = pooled + 64 * 16;                   // 64
  int*           count  = (int*)(cnt + 64);                   // N
  int*           row_off= count + N;                          // N+1
  int*           cursor = row_off + N + 1;                    // N
  int*           csr_src= cursor + N;                         // E+N
  int*           bcount = csr_src + E + N;                    // 128
  int*           bbase  = bcount + 128;                       // 128
  int*           bcur   = bbase + 128;                        // 128
  int*           psum   = bcur + 128;                         // SBN
  unsigned*      packed = (unsigned*)(psum + SBN);            // E

  const int K    = (N + BK - 1) / BK;                    // dst buckets
  const int nch  = cdiv_l(E, EPB);                       // edge chunks
  const int g8   = 8 * ((K + 7) / 8) * BPB;              // phase-2 grid

  // ---- build CSR by destination (bucket-partitioned; reused by all 5 layers) ----
  hipMemsetAsync(bcount, 0, 128 * 4, stream);
  hipMemsetAsync(count, 0, (size_t)N * 4, stream);
  bucket_hist_k<<<nch, TPB, 0, stream>>>(dst, bcount, E);
  bucket_scan_k<<<1, 128, 0, stream>>>(bcount, bbase, bcur, K);
  partition_k<<<nch, TPB, 0, stream>>>(src, dst, bcur, packed, E);
  nodehist_k<<<g8, TPB, 0, stream>>>(packed, bbase, bcur, count, K);
  partial_k<<<SBN, 256, 0, stream>>>(count, psum, N);
  pscan_k<<<1, SBN, 0, stream>>>(psum, SBN);
  rowoff_k<<<SBN, 256, 0, stream>>>(count, psum, row_off, N, E + N);
  cursor_k<<<cdiv_l(N, TPB), TPB, 0, stream>>>(row_off, cursor, csr_src, N);
  bscatter_k<<<g8, TPB, 0, stream>>>(packed, bbase, bcur, cursor, csr_src, K);

  const int gb = cdiv_l(N, 4);

  // layer 1: Fin=128, H=1, C=32
  gemm2_k<128,32,32><<<cdiv_l(N, 1024/32), 256, 0, stream>>>(x, W_[0], as_[0], ad_[0], es, ed, Hb, N);
  agg_k<1,32><<<gb, 256, 0, stream>>>(csr_src, row_off, es, ed, Hb, b_[0], f_buf, N);
  // layer 2: Fin=32, H=2, C=32
  gemm2_k<32,64,32><<<cdiv_l(N, 1024/64), 256, 0, stream>>>(f_buf, W_[1], as_[1], ad_[1], es, ed, Hb, N);
  agg_k<2,32><<<gb, 256, 0, stream>>>(csr_src, row_off, es, ed, Hb, b_[1], f_buf, N);
  // layer 3: Fin=64, H=2, C=64
  gemm2_k<64,128,64><<<cdiv_l(N, 1024/128), 256, 0, stream>>>(f_buf, W_[2], as_[2], ad_[2], es, ed, Hb, N);
  agg_k<2,64><<<gb, 256, 0, stream>>>(csr_src, row_off, es, ed, Hb, b_[2], f_buf, N);
  // layer 4: Fin=128, H=2, C=32
  gemm2_k<128,64,32><<<cdiv_l(N, 1024/64), 256, 0, stream>>>(f_buf, W_[3], as_[3], ad_[3], es, ed, Hb, N);
  agg_k<2,32><<<gb, 256, 0, stream>>>(csr_src, row_off, es, ed, Hb, b_[3], f_buf, N);
  // layer 5: Fin=64, H=2, C=8
  gemm2_k<64,16,8><<<cdiv_l(N, 1024/16), 256, 0, stream>>>(f_buf, W_[4], as_[4], ad_[4], es, ed, Hb, N);
  agg_k<2,8><<<gb, 256, 0, stream>>>(csr_src, row_off, es, ed, Hb, b_[4], f_buf, N);

  // global mean pool (G=64) + FC + sigmoid
  hipMemsetAsync(pooled, 0, (64 * 16 + 64) * 4, stream);
  pool_k<<<64, 256, 0, stream>>>(f_buf, batch, pooled, cnt, N);
  final_fc_k<<<1, 64, 0, stream>>>(pooled, cnt, fcW, fcb, outp);
}

// Round 14
// 393.281 us; speedup vs baseline: 1.5216x; 1.1113x over previous
//
#include <hip/hip_runtime.h>
#include <math.h>

#define TPB 256
#define NEG_SLOPE 0.2f
#define EPB 2048          // edges per block-chunk in streaming CSR kernels
#define BK 512            // nodes per bucket (dst>>9)
#define BPB 8             // blocks per bucket in phase-2 kernels
#define SBN 256           // blocks in multi-block scan

static inline int cdiv_l(long a, int b){ return (int)((a + b - 1) / b); }

typedef float v2f __attribute__((ext_vector_type(2)));

__device__ __forceinline__ ushort f2bf(float f){
  unsigned u = __float_as_uint(f);
  unsigned r = u + 0x7fffu + ((u >> 16) & 1u);   // RNE
  return (ushort)(r >> 16);
}
__device__ __forceinline__ float bf2f(unsigned hi16){ return __uint_as_float(hi16 << 16); }
__device__ __forceinline__ unsigned pbf2(float a, float b){
  return (unsigned)f2bf(a) | ((unsigned)f2bf(b) << 16);
}

// ---------------- GEMM + fused attention dots + fp8 payload + bf16 act write ----------------
template<int Fin, int HC, int C, typename XT>
__global__ __launch_bounds__(256) void gemm2_k(const XT* __restrict__ X,
        const float* __restrict__ W, const float* __restrict__ as_,
        const float* __restrict__ ad_, float* __restrict__ es, float* __restrict__ ed,
        unsigned char* __restrict__ Hb, int N){
  constexpr int TPN = HC / 4;         // threads per node
  constexpr int NPB = 256 / TPN;      // nodes per block
  constexpr int H   = HC / C;
  constexpr int RG  = C / 4;          // lanes per (node, head)
  __shared__ float Wl[Fin * HC];
  for (int i = threadIdx.x; i < Fin * HC; i += 256) Wl[i] = W[i];
  __syncthreads();
  const int t  = threadIdx.x;
  const int n  = blockIdx.x * NPB + t / TPN;
  const int jt = (t % TPN) * 4;
  if (n >= N) return;
  const XT* xr = X + (size_t)n * Fin;
  float acc[4] = {0.f, 0.f, 0.f, 0.f};
  for (int k = 0; k < Fin; k += 4){
    float xv[4];
    if constexpr (sizeof(XT) == 4){
      float4 v = *(const float4*)(xr + k);
      xv[0] = v.x; xv[1] = v.y; xv[2] = v.z; xv[3] = v.w;
    } else {
      uint2 u = *(const uint2*)(xr + k);
      xv[0] = bf2f(u.x & 0xffffu); xv[1] = bf2f(u.x >> 16);
      xv[2] = bf2f(u.y & 0xffffu); xv[3] = bf2f(u.y >> 16);
    }
#pragma unroll
    for (int kk = 0; kk < 4; ++kk){
#pragma unroll
      for (int j = 0; j < 4; ++j)
        acc[j] = fmaf(xv[kk], Wl[(k + kk) * HC + jt + j], acc[j]);
    }
  }
  // fp8 e4m3 payload write (4B per thread, coalesced), HW packed convert
  int pk8 = __builtin_amdgcn_cvt_pk_fp8_f32(acc[0], acc[1], 0, false);
  pk8     = __builtin_amdgcn_cvt_pk_fp8_f32(acc[2], acc[3], pk8, true);
  *(int*)(Hb + (size_t)n * HC + jt) = pk8;
  // fused attention dots (from unquantized fp32 accumulators)
  const int head = jt / C, col = jt % C;
  float ps = 0.f, pd = 0.f;
#pragma unroll
  for (int j = 0; j < 4; ++j){
    ps = fmaf(acc[j], as_[head * C + col + j], ps);
    pd = fmaf(acc[j], ad_[head * C + col + j], pd);
  }
#pragma unroll
  for (int off = RG >> 1; off >= 1; off >>= 1){
    ps += __shfl_xor(ps, off);
    pd += __shfl_xor(pd, off);
  }
  if ((t % RG) == 0){
    es[n * H + head] = ps;
    ed[n * H + head] = pd;
  }
}

// ---------------- CSR build: two-phase bucket partition ----------------

__global__ __launch_bounds__(256) void bucket_hist_k(const int* __restrict__ dst,
                        int* __restrict__ bcount, int E){
  __shared__ int lh[128];
  const int t = threadIdx.x;
  for (int i = t; i < 128; i += TPB) lh[i] = 0;
  __syncthreads();
  const int c0 = blockIdx.x * EPB;
  int i1 = c0 + EPB; if (i1 > E) i1 = E;
  for (int i = c0 + t; i < i1; i += TPB)
    atomicAdd(&lh[dst[i] >> 9], 1);
  __syncthreads();
  for (int i = t; i < 128; i += TPB)
    if (lh[i]) atomicAdd(&bcount[i], lh[i]);
}

__global__ void bucket_scan_k(const int* __restrict__ bcount,
                              int* __restrict__ bbase, int* __restrict__ bcur, int K){
  __shared__ int v[128];
  const int t = threadIdx.x;     // 128 threads
  int orig = (t < K) ? bcount[t] : 0;
  v[t] = orig; __syncthreads();
  for (int off = 1; off < 128; off <<= 1){
    int y = (t >= off) ? v[t - off] : 0;
    __syncthreads();
    v[t] += y;
    __syncthreads();
  }
  int excl = v[t] - orig;
  if (t < K){ bbase[t] = excl; bcur[t] = excl; }
}

__global__ __launch_bounds__(256) void partition_k(const int* __restrict__ src,
                        const int* __restrict__ dst,
                        int* __restrict__ bcur, unsigned* __restrict__ packed, int E){
  __shared__ int lh[128];     // per-bucket local count, then local rank cursor
  __shared__ int lofs[128];   // global base reserved for this block
  const int t = threadIdx.x;
  for (int i = t; i < 128; i += TPB) lh[i] = 0;
  __syncthreads();
  const int c0 = blockIdx.x * EPB;
  int i1 = c0 + EPB; if (i1 > E) i1 = E;
  for (int i = c0 + t; i < i1; i += TPB)
    atomicAdd(&lh[dst[i] >> 9], 1);
  __syncthreads();
  if (t < 128){
    lofs[t] = lh[t] ? atomicAdd(&bcur[t], lh[t]) : 0;
    lh[t] = 0;
  }
  __syncthreads();
  for (int i = c0 + t; i < i1; i += TPB){
    int d = dst[i], k = d >> 9;
    int r = atomicAdd(&lh[k], 1);                       // LDS rank
    packed[lofs[k] + r] = ((unsigned)src[i] << 9) | (unsigned)(d & 511);
  }
}

// Phase 2: per bucket (8 blocks, same XCD via blockIdx&7)

__device__ __forceinline__ bool bucket_range(const int* bbase, const int* bcur,
        int K, int& k, int& i0, int& i1, int& nb){
  const int slice = blockIdx.x & 7;
  const int q = blockIdx.x >> 3;
  const int kk = q / BPB, c = q % BPB;
  k = kk * 8 + slice;
  if (k >= K) return false;
  const int b0 = bbase[k];
  const int sz = bcur[k] - b0;
  const int per = (sz + BPB - 1) / BPB;
  i0 = b0 + c * per;
  i1 = b0 + sz; if (i0 + per < i1) i1 = i0 + per;
  nb = k << 9;
  return i0 < i1;
}

__global__ __launch_bounds__(256) void nodehist_k(const unsigned* __restrict__ packed,
                        const int* __restrict__ bbase, const int* __restrict__ bcur,
                        int* __restrict__ count, int K){
  int k, i0, i1, nb;
  if (!bucket_range(bbase, bcur, K, k, i0, i1, nb)) return;
  for (int i = i0 + threadIdx.x; i < i1; i += TPB){
    unsigned pk = packed[i];
    atomicAdd(&count[nb + (int)(pk & 511u)], 1);
  }
}

// ---------------- multi-block scan of count[i]+1 -> row_off (+cursor fused) -------

__global__ __launch_bounds__(256) void partial_k(const int* __restrict__ count,
                        int* __restrict__ psum, int N){
  const int per = (N + gridDim.x - 1) / gridDim.x;
  const int b0 = blockIdx.x * per;
  int b1 = b0 + per; if (b1 > N) b1 = N;
  int s = 0;
  for (int i = b0 + threadIdx.x; i < b1; i += 256) s += count[i] + 1;
#pragma unroll
  for (int off = 32; off >= 1; off >>= 1) s += __shfl_xor(s, off);
  __shared__ int ws[4];
  if ((threadIdx.x & 63) == 0) ws[threadIdx.x >> 6] = s;
  __syncthreads();
  if (threadIdx.x == 0) psum[blockIdx.x] = ws[0] + ws[1] + ws[2] + ws[3];
}

__global__ void pscan_k(int* __restrict__ psum, int n){
  __shared__ int v[SBN];
  const int t = threadIdx.x;
  int orig = (t < n) ? psum[t] : 0;
  v[t] = orig; __syncthreads();
  for (int off = 1; off < SBN; off <<= 1){
    int y = (t >= off) ? v[t - off] : 0;
    __syncthreads();
    v[t] += y;
    __syncthreads();
  }
  if (t < n) psum[t] = v[t] - orig;   // exclusive
}

__global__ __launch_bounds__(256) void rowoff_k(const int* __restrict__ count,
                        const int* __restrict__ psum, int* __restrict__ row_off,
                        int* __restrict__ cursor, int* __restrict__ csr_src,
                        int N, int total){
  const int per = (N + gridDim.x - 1) / gridDim.x;
  const int b0 = blockIdx.x * per;
  int b1 = b0 + per; if (b1 > N) b1 = N;
  int base = psum[blockIdx.x];
  __shared__ int tile[256];
  const int t = threadIdx.x;
  for (int start = b0; start < b1; start += 256){
    int i = start + t;
    int v = (i < b1) ? count[i] + 1 : 0;
    tile[t] = v; __syncthreads();
    for (int off = 1; off < 256; off <<= 1){
      int y = (t >= off) ? tile[t - off] : 0;
      __syncthreads();
      tile[t] += y;
      __syncthreads();
    }
    if (i < b1){
      int r = base + tile[t] - v;
      row_off[i] = r;
      csr_src[r] = i;          // self-loop occupies first slot
      cursor[i] = r + 1;
    }
    base += tile[255];
    __syncthreads();
  }
  if (blockIdx.x == 0 && t == 0) row_off[N] = total;
}

__global__ __launch_bounds__(256) void bscatter_k(const unsigned* __restrict__ packed,
                        const int* __restrict__ bbase, const int* __restrict__ bcur,
                        int* __restrict__ cursor, int* __restrict__ csr_src, int K){
  int k, i0, i1, nb;
  if (!bucket_range(bbase, bcur, K, k, i0, i1, nb)) return;
  for (int i = i0 + threadIdx.x; i < i1; i += TPB){
    unsigned pk = packed[i];
    int d = nb + (int)(pk & 511u);
    int p = atomicAdd(&cursor[d], 1);
    csr_src[p] = (int)(pk >> 9);
  }
}

// ---------------- fused single-pass softmax + aggregate + bias + relu ----------------
// one wave per destination node; fp8 e4m3 payload (HW cvt), fp32 accumulate,
// bf16 activation output. 2x-unrolled gather loop for MLP; H=2 edge weights
// broadcast as packed bf16 (1 shfl). Invalid slots carry t=0 -> branch-free.

template<int H, int C>
__global__ __launch_bounds__(256) void agg_k(const int* __restrict__ csr_src,
        const int* __restrict__ row_off,
        const float* __restrict__ es, const float* __restrict__ ed,
        const unsigned char* __restrict__ Hb, const float* __restrict__ b,
        ushort* __restrict__ outp, int N){
  constexpr int HC  = H * C;
  constexpr int LPE = HC / 8;         // lanes per edge
  constexpr int EPW = 64 / LPE;       // edges per wave-iteration
  const int lane = threadIdx.x & 63;
  const int wv   = threadIdx.x >> 6;
  const int n = blockIdx.x * 4 + wv;
  if (n >= N) return;
  const int beg = row_off[n];
  const int deg = row_off[n + 1] - beg;

  const int grp  = lane / LPE;        // which edge slot this lane serves
  const int cpos = lane % LPE;        // which 8-channel group
  const int c0   = cpos * 8;
  const int hd   = c0 / C;            // head of this lane's channels (8<=C)

  float edn[H];
#pragma unroll
  for (int h = 0; h < H; ++h) edn[h] = ed[n * H + h];

  float den[H];
#pragma unroll
  for (int h = 0; h < H; ++h) den[h] = 0.f;
  float acc[8] = {0.f,0.f,0.f,0.f,0.f,0.f,0.f,0.f};

  for (int base = 0; base < deg; base += 64){
    int j = base + lane;
    float t0f = 0.f; unsigned tpk = 0; int sidx = 0;
    if (j < deg){
      sidx = csr_src[beg + j];
      if (H == 2){
        float2 e2 = *(const float2*)(es + sidx * 2);
        float ea = e2.x + edn[0];
        ea = ea > 0.f ? ea : ea * NEG_SLOPE;
        ea = fminf(ea, 80.f);
        float ta = __expf(ea);
        float eb = e2.y + edn[1];
        eb = eb > 0.f ? eb : eb * NEG_SLOPE;
        eb = fminf(eb, 80.f);
        float tb = __expf(eb);
        den[0] += ta; den[1] += tb;
        tpk = pbf2(ta, tb);
      } else {
        float e = es[sidx] + edn[0];
        e = e > 0.f ? e : e * NEG_SLOPE;
        e = fminf(e, 80.f);
        t0f = __expf(e);
        den[0] += t0f;
      }
    }
    int cnt = deg - base; if (cnt > 64) cnt = 64;

    int i = 0;
    // 2x unrolled: two independent gathers in flight
    for (; i + EPW < cnt; i += 2 * EPW){
      int sl0 = i + grp, sl1 = sl0 + EPW;
      int sj0 = __shfl(sidx, sl0);
      int sj1 = __shfl(sidx, sl1);
      float tf0, tf1;
      if (H == 2){
        unsigned w0 = (unsigned)__shfl((int)tpk, sl0);
        unsigned w1 = (unsigned)__shfl((int)tpk, sl1);
        tf0 = bf2f(hd ? (w0 >> 16) : (w0 & 0xffffu));
        tf1 = bf2f(hd ? (w1 >> 16) : (w1 & 0xffffu));
      } else {
        tf0 = __shfl(t0f, sl0);
        tf1 = __shfl(t0f, sl1);
      }
      const unsigned char* hr0 = Hb + (size_t)sj0 * HC + c0;
      const unsigned char* hr1 = Hb + (size_t)sj1 * HC + c0;
      uint2 v0 = *(const uint2*)hr0;
      uint2 v1 = *(const uint2*)hr1;
      v2f p0 = __builtin_amdgcn_cvt_pk_f32_fp8((int)v0.x, false);
      v2f p1 = __builtin_amdgcn_cvt_pk_f32_fp8((int)v0.x, true);
      v2f p2 = __builtin_amdgcn_cvt_pk_f32_fp8((int)v0.y, false);
      v2f p3 = __builtin_amdgcn_cvt_pk_f32_fp8((int)v0.y, true);
      acc[0] = fmaf(tf0, p0[0], acc[0]); acc[1] = fmaf(tf0, p0[1], acc[1]);
      acc[2] = fmaf(tf0, p1[0], acc[2]); acc[3] = fmaf(tf0, p1[1], acc[3]);
      acc[4] = fmaf(tf0, p2[0], acc[4]); acc[5] = fmaf(tf0, p2[1], acc[5]);
      acc[6] = fmaf(tf0, p3[0], acc[6]); acc[7] = fmaf(tf0, p3[1], acc[7]);
      v2f q0 = __builtin_amdgcn_cvt_pk_f32_fp8((int)v1.x, false);
      v2f q1 = __builtin_amdgcn_cvt_pk_f32_fp8((int)v1.x, true);
      v2f q2 = __builtin_amdgcn_cvt_pk_f32_fp8((int)v1.y, false);
      v2f q3 = __builtin_amdgcn_cvt_pk_f32_fp8((int)v1.y, true);
      acc[0] = fmaf(tf1, q0[0], acc[0]); acc[1] = fmaf(tf1, q0[1], acc[1]);
      acc[2] = fmaf(tf1, q1[0], acc[2]); acc[3] = fmaf(tf1, q1[1], acc[3]);
      acc[4] = fmaf(tf1, q2[0], acc[4]); acc[5] = fmaf(tf1, q2[1], acc[5]);
      acc[6] = fmaf(tf1, q3[0], acc[6]); acc[7] = fmaf(tf1, q3[1], acc[7]);
    }
    for (; i < cnt; i += EPW){
      int sl = i + grp;
      int sj = __shfl(sidx, sl);
      float tf;
      if (H == 2){
        unsigned w = (unsigned)__shfl((int)tpk, sl);
        tf = bf2f(hd ? (w >> 16) : (w & 0xffffu));
      } else {
        tf = __shfl(t0f, sl);
      }
      const unsigned char* hr = Hb + (size_t)sj * HC + c0;
      uint2 v = *(const uint2*)hr;
      v2f p0 = __builtin_amdgcn_cvt_pk_f32_fp8((int)v.x, false);
      v2f p1 = __builtin_amdgcn_cvt_pk_f32_fp8((int)v.x, true);
      v2f p2 = __builtin_amdgcn_cvt_pk_f32_fp8((int)v.y, false);
      v2f p3 = __builtin_amdgcn_cvt_pk_f32_fp8((int)v.y, true);
      acc[0] = fmaf(tf, p0[0], acc[0]); acc[1] = fmaf(tf, p0[1], acc[1]);
      acc[2] = fmaf(tf, p1[0], acc[2]); acc[3] = fmaf(tf, p1[1], acc[3]);
      acc[4] = fmaf(tf, p2[0], acc[4]); acc[5] = fmaf(tf, p2[1], acc[5]);
      acc[6] = fmaf(tf, p3[0], acc[6]); acc[7] = fmaf(tf, p3[1], acc[7]);
    }
  }

  // reduce denominators across the wave
  float sinv[H];
#pragma unroll
  for (int h = 0; h < H; ++h){
    float v = den[h];
#pragma unroll
    for (int off = 32; off >= 1; off >>= 1) v += __shfl_xor(v, off);
    sinv[h] = 1.f / v;
  }

  // reduce partial channel sums across edge-slot groups
#pragma unroll
  for (int off = LPE; off < 64; off <<= 1){
#pragma unroll
    for (int k = 0; k < 8; ++k) acc[k] += __shfl_xor(acc[k], off);
  }

  if (grp == 0){
    float si = sinv[hd];
    float o[8];
#pragma unroll
    for (int k = 0; k < 8; ++k){
      float v = fmaf(acc[k], si, b[c0 + k]);
      o[k] = v > 0.f ? v : 0.f;
    }
    uint4 w;
    w.x = pbf2(o[0], o[1]); w.y = pbf2(o[2], o[3]);
    w.z = pbf2(o[4], o[5]); w.w = pbf2(o[6], o[7]);
    *(uint4*)(outp + (size_t)n * HC + c0) = w;
  }
}

// ---------------- pooling + FC ----------------

__global__ __launch_bounds__(256) void pool_k(const ushort* __restrict__ f,
                       const int* __restrict__ batch,
                       float* __restrict__ pooled, float* __restrict__ cnt, int N){
  __shared__ float sp[64 * 16];
  __shared__ float sc[64];
  const int t = threadIdx.x;
  for (int i = t; i < 64 * 16; i += 256) sp[i] = 0.f;
  for (int i = t; i < 64; i += 256) sc[i] = 0.f;
  __syncthreads();
  const int per = (N + gridDim.x - 1) / gridDim.x;
  const int n0 = blockIdx.x * per;
  int n1 = n0 + per; if (n1 > N) n1 = N;
  const int nloc = t >> 4, c = t & 15;
  for (int n = n0 + nloc; n < n1; n += 16){
    int g = batch[n];
    atomicAdd(&sp[g * 16 + c], bf2f(f[(size_t)n * 16 + c]));
    if (c == 0) atomicAdd(&sc[g], 1.f);
  }
  __syncthreads();
  for (int i = t; i < 64 * 16; i += 256) if (sp[i] != 0.f) atomicAdd(&pooled[i], sp[i]);
  for (int i = t; i < 64; i += 256)      if (sc[i] != 0.f) atomicAdd(&cnt[i], sc[i]);
}

__global__ void final_fc_k(const float* __restrict__ pooled, const float* __restrict__ cnt,
                           const float* __restrict__ fcW, const float* __restrict__ fcb,
                           float* __restrict__ outp){
  int g = threadIdx.x;
  if (g >= 64) return;
  float c = cnt[g]; c = c > 1.f ? c : 1.f;
  float inv = 1.0f / c;
  float acc = fcb[0];
  for (int i = 0; i < 16; ++i) acc = fmaf(pooled[g * 16 + i] * inv, fcW[i], acc);
  outp[g] = 1.0f / (1.0f + expf(-acc));
}

// ---------------- driver ----------------

extern "C" void kernel_launch(void* const* d_in, const int* in_sizes, int n_in,
                              void* d_out, int out_size, void* d_ws, size_t ws_size,
                              hipStream_t stream) {
  const float* x    = (const float*)d_in[0];
  const int*  ei    = (const int*)d_in[1];
  const int*  batch = (const int*)d_in[2];

  const int N = in_sizes[0] / 128;
  const int E = in_sizes[1] / 2;

  const int* src = ei;
  const int* dst = ei + E;

  const float* W_[5];  const float* as_[5]; const float* ad_[5]; const float* b_[5];
  for (int l = 0; l < 5; ++l) {
    W_[l]  = (const float*)d_in[3 + 4 * l + 0];
    as_[l] = (const float*)d_in[3 + 4 * l + 1];
    ad_[l] = (const float*)d_in[3 + 4 * l + 2];
    b_[l]  = (const float*)d_in[3 + 4 * l + 3];
  }
  const float* fcW = (const float*)d_in[23];
  const float* fcb = (const float*)d_in[24];
  float* outp = (float*)d_out;

  // workspace layout
  ushort*        f_buf  = (ushort*)d_ws;                      // N*128 bf16 activations
  unsigned char* Hb     = (unsigned char*)(f_buf + (size_t)N * 128); // N*128 fp8 payload
  float*         es     = (float*)(Hb + (size_t)N * 128);     // N*2
  float*         ed     = es + (size_t)N * 2;                 // N*2
  float*         pooled = ed + (size_t)N * 2;                 // 64*16
  float*         cnt    = pooled + 64 * 16;                   // 64
  int*           count  = (int*)(cnt + 64);                   // N
  int*           bcount = count + N;                          // 128 (adjacent: one memset)
  int*           bbase  = bcount + 128;                       // 128
  int*           bcur   = bbase + 128;                        // 128
  int*           psum   = bcur + 128;                         // SBN
  int*           row_off= psum + SBN;                         // N+1
  int*           cursor = row_off + N + 1;                    // N
  int*           csr_src= cursor + N;                         // E+N
  unsigned*      packed = (unsigned*)(csr_src + E + N);       // E

  const int K    = (N + BK - 1) / BK;                    // dst buckets
  const int nch  = cdiv_l(E, EPB);                       // edge chunks
  const int g8   = 8 * ((K + 7) / 8) * BPB;              // phase-2 grid

  // ---- build CSR by destination (bucket-partitioned; reused by all 5 layers) ----
  hipMemsetAsync(count, 0, ((size_t)N + 128) * 4, stream);   // count + bcount
  bucket_hist_k<<<nch, TPB, 0, stream>>>(dst, bcount, E);
  bucket_scan_k<<<1, 128, 0, stream>>>(bcount, bbase, bcur, K);
  partition_k<<<nch, TPB, 0, stream>>>(src, dst, bcur, packed, E);
  nodehist_k<<<g8, TPB, 0, stream>>>(packed, bbase, bcur, count, K);
  partial_k<<<SBN, 256, 0, stream>>>(count, psum, N);
  pscan_k<<<1, SBN, 0, stream>>>(psum, SBN);
  rowoff_k<<<SBN, 256, 0, stream>>>(count, psum, row_off, cursor, csr_src, N, E + N);
  bscatter_k<<<g8, TPB, 0, stream>>>(packed, bbase, bcur, cursor, csr_src, K);

  const int gb = cdiv_l(N, 4);

  // layer 1: Fin=128, H=1, C=32 (fp32 input)
  gemm2_k<128,32,32,float><<<cdiv_l(N, 1024/32), 256, 0, stream>>>(x, W_[0], as_[0], ad_[0], es, ed, Hb, N);
  agg_k<1,32><<<gb, 256, 0, stream>>>(csr_src, row_off, es, ed, Hb, b_[0], f_buf, N);
  // layer 2: Fin=32, H=2, C=32
  gemm2_k<32,64,32,ushort><<<cdiv_l(N, 1024/64), 256, 0, stream>>>(f_buf, W_[1], as_[1], ad_[1], es, ed, Hb, N);
  agg_k<2,32><<<gb, 256, 0, stream>>>(csr_src, row_off, es, ed, Hb, b_[1], f_buf, N);
  // layer 3: Fin=64, H=2, C=64
  gemm2_k<64,128,64,ushort><<<cdiv_l(N, 1024/128), 256, 0, stream>>>(f_buf, W_[2], as_[2], ad_[2], es, ed, Hb, N);
  agg_k<2,64><<<gb, 256, 0, stream>>>(csr_src, row_off, es, ed, Hb, b_[2], f_buf, N);
  // layer 4: Fin=128, H=2, C=32
  gemm2_k<128,64,32,ushort><<<cdiv_l(N, 1024/64), 256, 0, stream>>>(f_buf, W_[3], as_[3], ad_[3], es, ed, Hb, N);
  agg_k<2,32><<<gb, 256, 0, stream>>>(csr_src, row_off, es, ed, Hb, b_[3], f_buf, N);
  // layer 5: Fin=64, H=2, C=8
  gemm2_k<64,16,8,ushort><<<cdiv_l(N, 1024/16), 256, 0, stream>>>(f_buf, W_[4], as_[4], ad_[4], es, ed, Hb, N);
  agg_k<2,8><<<gb, 256, 0, stream>>>(csr_src, row_off, es, ed, Hb, b_[4], f_buf, N);

  // global mean pool (G=64) + FC + sigmoid
  hipMemsetAsync(pooled, 0, (64 * 16 + 64) * 4, stream);
  pool_k<<<64, 256, 0, stream>>>(f_buf, batch, pooled, cnt, N);
  final_fc_k<<<1, 64, 0, stream>>>(pooled, cnt, fcW, fcb, outp);
}

// Round 15
// 345.152 us; speedup vs baseline: 1.7338x; 1.1394x over previous
//
#include <hip/hip_runtime.h>
#include <math.h>

#define TPB 256
#define NEG_SLOPE 0.2f
#define EPB 2048          // edges per block-chunk in streaming CSR kernels
#define BK 512            // nodes per bucket (dst>>9)

static inline int cdiv_l(long a, int b){ return (int)((a + b - 1) / b); }

typedef float v2f __attribute__((ext_vector_type(2)));

__device__ __forceinline__ ushort f2bf(float f){
  unsigned u = __float_as_uint(f);
  unsigned r = u + 0x7fffu + ((u >> 16) & 1u);   // RNE
  return (ushort)(r >> 16);
}
__device__ __forceinline__ float bf2f(unsigned hi16){ return __uint_as_float(hi16 << 16); }
__device__ __forceinline__ unsigned pbf2(float a, float b){
  return (unsigned)f2bf(a) | ((unsigned)f2bf(b) << 16);
}

// ---------------- GEMM + fused attention dots + fp8 payload + bf16 act write ----------------
template<int Fin, int HC, int C, typename XT>
__global__ __launch_bounds__(256) void gemm2_k(const XT* __restrict__ X,
        const float* __restrict__ W, const float* __restrict__ as_,
        const float* __restrict__ ad_, float* __restrict__ es, float* __restrict__ ed,
        unsigned char* __restrict__ Hb, int N){
  constexpr int TPN = HC / 4;         // threads per node
  constexpr int NPB = 256 / TPN;      // nodes per block
  constexpr int H   = HC / C;
  constexpr int RG  = C / 4;          // lanes per (node, head)
  __shared__ float Wl[Fin * HC];
  for (int i = threadIdx.x; i < Fin * HC; i += 256) Wl[i] = W[i];
  __syncthreads();
  const int t  = threadIdx.x;
  const int n  = blockIdx.x * NPB + t / TPN;
  const int jt = (t % TPN) * 4;
  if (n >= N) return;
  const XT* xr = X + (size_t)n * Fin;
  float acc[4] = {0.f, 0.f, 0.f, 0.f};
  for (int k = 0; k < Fin; k += 4){
    float xv[4];
    if constexpr (sizeof(XT) == 4){
      float4 v = *(const float4*)(xr + k);
      xv[0] = v.x; xv[1] = v.y; xv[2] = v.z; xv[3] = v.w;
    } else {
      uint2 u = *(const uint2*)(xr + k);
      xv[0] = bf2f(u.x & 0xffffu); xv[1] = bf2f(u.x >> 16);
      xv[2] = bf2f(u.y & 0xffffu); xv[3] = bf2f(u.y >> 16);
    }
#pragma unroll
    for (int kk = 0; kk < 4; ++kk){
#pragma unroll
      for (int j = 0; j < 4; ++j)
        acc[j] = fmaf(xv[kk], Wl[(k + kk) * HC + jt + j], acc[j]);
    }
  }
  int pk8 = __builtin_amdgcn_cvt_pk_fp8_f32(acc[0], acc[1], 0, false);
  pk8     = __builtin_amdgcn_cvt_pk_fp8_f32(acc[2], acc[3], pk8, true);
  *(int*)(Hb + (size_t)n * HC + jt) = pk8;
  const int head = jt / C, col = jt % C;
  float ps = 0.f, pd = 0.f;
#pragma unroll
  for (int j = 0; j < 4; ++j){
    ps = fmaf(acc[j], as_[head * C + col + j], ps);
    pd = fmaf(acc[j], ad_[head * C + col + j], pd);
  }
#pragma unroll
  for (int off = RG >> 1; off >= 1; off >>= 1){
    ps += __shfl_xor(ps, off);
    pd += __shfl_xor(pd, off);
  }
  if ((t % RG) == 0){
    es[n * H + head] = ps;
    ed[n * H + head] = pd;
  }
}

// ---------------- CSR build: bucket partition + per-bucket counting sort ----------------

__global__ __launch_bounds__(256) void bucket_hist_k(const int* __restrict__ dst,
                        int* __restrict__ bcount, int E){
  __shared__ int lh[128];
  const int t = threadIdx.x;
  for (int i = t; i < 128; i += TPB) lh[i] = 0;
  __syncthreads();
  const int c0 = blockIdx.x * EPB;
  int i1 = c0 + EPB; if (i1 > E) i1 = E;
  for (int i = c0 + t; i < i1; i += TPB)
    atomicAdd(&lh[dst[i] >> 9], 1);
  __syncthreads();
  for (int i = t; i < 128; i += TPB)
    if (lh[i]) atomicAdd(&bcount[i], lh[i]);
}

__global__ void bucket_scan_k(const int* __restrict__ bcount,
                              int* __restrict__ bbase, int* __restrict__ bcur, int K){
  __shared__ int v[128];
  const int t = threadIdx.x;     // 128 threads
  int orig = (t < K) ? bcount[t] : 0;
  v[t] = orig; __syncthreads();
  for (int off = 1; off < 128; off <<= 1){
    int y = (t >= off) ? v[t - off] : 0;
    __syncthreads();
    v[t] += y;
    __syncthreads();
  }
  int excl = v[t] - orig;
  if (t < K){ bbase[t] = excl; bcur[t] = excl; }
}

__global__ __launch_bounds__(256) void partition_k(const int* __restrict__ src,
                        const int* __restrict__ dst,
                        int* __restrict__ bcur, unsigned* __restrict__ packed, int E){
  __shared__ int lh[128];     // per-bucket local count, then local rank cursor
  __shared__ int lofs[128];   // global base reserved for this block
  const int t = threadIdx.x;
  for (int i = t; i < 128; i += TPB) lh[i] = 0;
  __syncthreads();
  const int c0 = blockIdx.x * EPB;
  int i1 = c0 + EPB; if (i1 > E) i1 = E;
  for (int i = c0 + t; i < i1; i += TPB)
    atomicAdd(&lh[dst[i] >> 9], 1);
  __syncthreads();
  if (t < 128){
    lofs[t] = lh[t] ? atomicAdd(&bcur[t], lh[t]) : 0;
    lh[t] = 0;
  }
  __syncthreads();
  for (int i = c0 + t; i < i1; i += TPB){
    int d = dst[i], k = d >> 9;
    int r = atomicAdd(&lh[k], 1);                       // LDS rank
    packed[lofs[k] + r] = ((unsigned)src[i] << 9) | (unsigned)(d & 511);
  }
}

// One block per bucket: LDS histogram over the bucket's packed segment, LDS
// scan, then write row_off (coalesced), self-loop slots, and scatter the
// segment into the bucket's contiguous csr window. Global base for bucket k
// is analytic: bbase[k] edges + k*BK self-loops — no global N-scan needed.
// All writes to a csr line happen from one block within a tight window ->
// write amplification ~1x.
__global__ __launch_bounds__(256) void bucket_csr_k(const unsigned* __restrict__ packed,
                        const int* __restrict__ bbase, const int* __restrict__ bcur,
                        int* __restrict__ row_off, int* __restrict__ csr_src,
                        int N, int E, int K){
  __shared__ int hist[BK];
  __shared__ int cur[BK];
  __shared__ int scan2[256];
  const int k = blockIdx.x;
  const int t = threadIdx.x;
  const int b0 = bbase[k], b1 = bcur[k];
  const int nb = k * BK;
  int nloc = N - nb; if (nloc > BK) nloc = BK;

  for (int i = t; i < BK; i += 256) hist[i] = 0;
  __syncthreads();
  for (int i = b0 + t; i < b1; i += 256)
    atomicAdd(&hist[packed[i] & 511u], 1);
  __syncthreads();

  // exclusive scan of hist[0..BK) with 256 threads, 2 elems/thread
  int a0 = hist[2 * t], a1 = hist[2 * t + 1];
  int pair = a0 + a1;
  scan2[t] = pair; __syncthreads();
  for (int off = 1; off < 256; off <<= 1){
    int y = (t >= off) ? scan2[t - off] : 0;
    __syncthreads();
    scan2[t] += y;
    __syncthreads();
  }
  int pexcl = scan2[t] - pair;            // exclusive over pairs
  const int base = b0 + nb;               // global entry index of this bucket
  // node 2t and 2t+1: row_off, self-loop slot, cursor
  int i0 = 2 * t, i1n = 2 * t + 1;
  if (i0 < nloc){
    int r = base + pexcl + i0;            // + i0 self-loops within bucket
    row_off[nb + i0] = r;
    csr_src[r] = nb + i0;
    cur[i0] = r + 1;
  }
  if (i1n < nloc){
    int r = base + pexcl + a0 + i1n;
    row_off[nb + i1n] = r;
    csr_src[r] = nb + i1n;
    cur[i1n] = r + 1;
  }
  if (k == K - 1 && t == 0) row_off[N] = E + N;
  __syncthreads();

  for (int i = b0 + t; i < b1; i += 256){
    unsigned pk = packed[i];
    int p = atomicAdd(&cur[pk & 511u], 1);
    csr_src[p] = (int)(pk >> 9);
  }
}

// ---------------- fused single-pass softmax + aggregate + bias + relu ----------------
// one wave per destination node; fp8 e4m3 payload (HW cvt), fp32 accumulate,
// bf16 activation output. 2x-unrolled gather loop for MLP; H=2 edge weights
// broadcast as packed bf16 (1 shfl). Invalid slots carry t=0 -> branch-free.

template<int H, int C>
__global__ __launch_bounds__(256) void agg_k(const int* __restrict__ csr_src,
        const int* __restrict__ row_off,
        const float* __restrict__ es, const float* __restrict__ ed,
        const unsigned char* __restrict__ Hb, const float* __restrict__ b,
        ushort* __restrict__ outp, int N){
  constexpr int HC  = H * C;
  constexpr int LPE = HC / 8;         // lanes per edge
  constexpr int EPW = 64 / LPE;       // edges per wave-iteration
  const int lane = threadIdx.x & 63;
  const int wv   = threadIdx.x >> 6;
  const int n = blockIdx.x * 4 + wv;
  if (n >= N) return;
  const int beg = row_off[n];
  const int deg = row_off[n + 1] - beg;

  const int grp  = lane / LPE;        // which edge slot this lane serves
  const int cpos = lane % LPE;        // which 8-channel group
  const int c0   = cpos * 8;
  const int hd   = c0 / C;            // head of this lane's channels (8<=C)

  float edn[H];
#pragma unroll
  for (int h = 0; h < H; ++h) edn[h] = ed[n * H + h];

  float den[H];
#pragma unroll
  for (int h = 0; h < H; ++h) den[h] = 0.f;
  float acc[8] = {0.f,0.f,0.f,0.f,0.f,0.f,0.f,0.f};

  for (int base = 0; base < deg; base += 64){
    int j = base + lane;
    float t0f = 0.f; unsigned tpk = 0; int sidx = 0;
    if (j < deg){
      sidx = csr_src[beg + j];
      if (H == 2){
        float2 e2 = *(const float2*)(es + sidx * 2);
        float ea = e2.x + edn[0];
        ea = ea > 0.f ? ea : ea * NEG_SLOPE;
        ea = fminf(ea, 80.f);
        float ta = __expf(ea);
        float eb = e2.y + edn[1];
        eb = eb > 0.f ? eb : eb * NEG_SLOPE;
        eb = fminf(eb, 80.f);
        float tb = __expf(eb);
        den[0] += ta; den[1] += tb;
        tpk = pbf2(ta, tb);
      } else {
        float e = es[sidx] + edn[0];
        e = e > 0.f ? e : e * NEG_SLOPE;
        e = fminf(e, 80.f);
        t0f = __expf(e);
        den[0] += t0f;
      }
    }
    int cnt = deg - base; if (cnt > 64) cnt = 64;

    int i = 0;
    // 2x unrolled: two independent gathers in flight
    for (; i + EPW < cnt; i += 2 * EPW){
      int sl0 = i + grp, sl1 = sl0 + EPW;
      int sj0 = __shfl(sidx, sl0);
      int sj1 = __shfl(sidx, sl1);
      float tf0, tf1;
      if (H == 2){
        unsigned w0 = (unsigned)__shfl((int)tpk, sl0);
        unsigned w1 = (unsigned)__shfl((int)tpk, sl1);
        tf0 = bf2f(hd ? (w0 >> 16) : (w0 & 0xffffu));
        tf1 = bf2f(hd ? (w1 >> 16) : (w1 & 0xffffu));
      } else {
        tf0 = __shfl(t0f, sl0);
        tf1 = __shfl(t0f, sl1);
      }
      const unsigned char* hr0 = Hb + (size_t)sj0 * HC + c0;
      const unsigned char* hr1 = Hb + (size_t)sj1 * HC + c0;
      uint2 v0 = *(const uint2*)hr0;
      uint2 v1 = *(const uint2*)hr1;
      v2f p0 = __builtin_amdgcn_cvt_pk_f32_fp8((int)v0.x, false);
      v2f p1 = __builtin_amdgcn_cvt_pk_f32_fp8((int)v0.x, true);
      v2f p2 = __builtin_amdgcn_cvt_pk_f32_fp8((int)v0.y, false);
      v2f p3 = __builtin_amdgcn_cvt_pk_f32_fp8((int)v0.y, true);
      acc[0] = fmaf(tf0, p0[0], acc[0]); acc[1] = fmaf(tf0, p0[1], acc[1]);
      acc[2] = fmaf(tf0, p1[0], acc[2]); acc[3] = fmaf(tf0, p1[1], acc[3]);
      acc[4] = fmaf(tf0, p2[0], acc[4]); acc[5] = fmaf(tf0, p2[1], acc[5]);
      acc[6] = fmaf(tf0, p3[0], acc[6]); acc[7] = fmaf(tf0, p3[1], acc[7]);
      v2f q0 = __builtin_amdgcn_cvt_pk_f32_fp8((int)v1.x, false);
      v2f q1 = __builtin_amdgcn_cvt_pk_f32_fp8((int)v1.x, true);
      v2f q2 = __builtin_amdgcn_cvt_pk_f32_fp8((int)v1.y, false);
      v2f q3 = __builtin_amdgcn_cvt_pk_f32_fp8((int)v1.y, true);
      acc[0] = fmaf(tf1, q0[0], acc[0]); acc[1] = fmaf(tf1, q0[1], acc[1]);
      acc[2] = fmaf(tf1, q1[0], acc[2]); acc[3] = fmaf(tf1, q1[1], acc[3]);
      acc[4] = fmaf(tf1, q2[0], acc[4]); acc[5] = fmaf(tf1, q2[1], acc[5]);
      acc[6] = fmaf(tf1, q3[0], acc[6]); acc[7] = fmaf(tf1, q3[1], acc[7]);
    }
    for (; i < cnt; i += EPW){
      int sl = i + grp;
      int sj = __shfl(sidx, sl);
      float tf;
      if (H == 2){
        unsigned w = (unsigned)__shfl((int)tpk, sl);
        tf = bf2f(hd ? (w >> 16) : (w & 0xffffu));
      } else {
        tf = __shfl(t0f, sl);
      }
      const unsigned char* hr = Hb + (size_t)sj * HC + c0;
      uint2 v = *(const uint2*)hr;
      v2f p0 = __builtin_amdgcn_cvt_pk_f32_fp8((int)v.x, false);
      v2f p1 = __builtin_amdgcn_cvt_pk_f32_fp8((int)v.x, true);
      v2f p2 = __builtin_amdgcn_cvt_pk_f32_fp8((int)v.y, false);
      v2f p3 = __builtin_amdgcn_cvt_pk_f32_fp8((int)v.y, true);
      acc[0] = fmaf(tf, p0[0], acc[0]); acc[1] = fmaf(tf, p0[1], acc[1]);
      acc[2] = fmaf(tf, p1[0], acc[2]); acc[3] = fmaf(tf, p1[1], acc[3]);
      acc[4] = fmaf(tf, p2[0], acc[4]); acc[5] = fmaf(tf, p2[1], acc[5]);
      acc[6] = fmaf(tf, p3[0], acc[6]); acc[7] = fmaf(tf, p3[1], acc[7]);
    }
  }

  // reduce denominators across the wave
  float sinv[H];
#pragma unroll
  for (int h = 0; h < H; ++h){
    float v = den[h];
#pragma unroll
    for (int off = 32; off >= 1; off >>= 1) v += __shfl_xor(v, off);
    sinv[h] = 1.f / v;
  }

  // reduce partial channel sums across edge-slot groups
#pragma unroll
  for (int off = LPE; off < 64; off <<= 1){
#pragma unroll
    for (int k = 0; k < 8; ++k) acc[k] += __shfl_xor(acc[k], off);
  }

  if (grp == 0){
    float si = sinv[hd];
    float o[8];
#pragma unroll
    for (int k = 0; k < 8; ++k){
      float v = fmaf(acc[k], si, b[c0 + k]);
      o[k] = v > 0.f ? v : 0.f;
    }
    uint4 w;
    w.x = pbf2(o[0], o[1]); w.y = pbf2(o[2], o[3]);
    w.z = pbf2(o[4], o[5]); w.w = pbf2(o[6], o[7]);
    *(uint4*)(outp + (size_t)n * HC + c0) = w;
  }
}

// ---------------- pooling + FC ----------------

__global__ __launch_bounds__(256) void pool_k(const ushort* __restrict__ f,
                       const int* __restrict__ batch,
                       float* __restrict__ pooled, float* __restrict__ cnt, int N){
  __shared__ float sp[64 * 16];
  __shared__ float sc[64];
  const int t = threadIdx.x;
  for (int i = t; i < 64 * 16; i += 256) sp[i] = 0.f;
  for (int i = t; i < 64; i += 256) sc[i] = 0.f;
  __syncthreads();
  const int per = (N + gridDim.x - 1) / gridDim.x;
  const int n0 = blockIdx.x * per;
  int n1 = n0 + per; if (n1 > N) n1 = N;
  const int nloc = t >> 4, c = t & 15;
  for (int n = n0 + nloc; n < n1; n += 16){
    int g = batch[n];
    atomicAdd(&sp[g * 16 + c], bf2f(f[(size_t)n * 16 + c]));
    if (c == 0) atomicAdd(&sc[g], 1.f);
  }
  __syncthreads();
  for (int i = t; i < 64 * 16; i += 256) if (sp[i] != 0.f) atomicAdd(&pooled[i], sp[i]);
  for (int i = t; i < 64; i += 256)      if (sc[i] != 0.f) atomicAdd(&cnt[i], sc[i]);
}

__global__ void final_fc_k(const float* __restrict__ pooled, const float* __restrict__ cnt,
                           const float* __restrict__ fcW, const float* __restrict__ fcb,
                           float* __restrict__ outp){
  int g = threadIdx.x;
  if (g >= 64) return;
  float c = cnt[g]; c = c > 1.f ? c : 1.f;
  float inv = 1.0f / c;
  float acc = fcb[0];
  for (int i = 0; i < 16; ++i) acc = fmaf(pooled[g * 16 + i] * inv, fcW[i], acc);
  outp[g] = 1.0f / (1.0f + expf(-acc));
}

// ---------------- driver ----------------

extern "C" void kernel_launch(void* const* d_in, const int* in_sizes, int n_in,
                              void* d_out, int out_size, void* d_ws, size_t ws_size,
                              hipStream_t stream) {
  const float* x    = (const float*)d_in[0];
  const int*  ei    = (const int*)d_in[1];
  const int*  batch = (const int*)d_in[2];

  const int N = in_sizes[0] / 128;
  const int E = in_sizes[1] / 2;

  const int* src = ei;
  const int* dst = ei + E;

  const float* W_[5];  const float* as_[5]; const float* ad_[5]; const float* b_[5];
  for (int l = 0; l < 5; ++l) {
    W_[l]  = (const float*)d_in[3 + 4 * l + 0];
    as_[l] = (const float*)d_in[3 + 4 * l + 1];
    ad_[l] = (const float*)d_in[3 + 4 * l + 2];
    b_[l]  = (const float*)d_in[3 + 4 * l + 3];
  }
  const float* fcW = (const float*)d_in[23];
  const float* fcb = (const float*)d_in[24];
  float* outp = (float*)d_out;

  // workspace layout
  ushort*        f_buf  = (ushort*)d_ws;                      // N*128 bf16 activations
  unsigned char* Hb     = (unsigned char*)(f_buf + (size_t)N * 128); // N*128 fp8 payload
  float*         es     = (float*)(Hb + (size_t)N * 128);     // N*2
  float*         ed     = es + (size_t)N * 2;                 // N*2
  float*         pooled = ed + (size_t)N * 2;                 // 64*16
  float*         cnt    = pooled + 64 * 16;                   // 64
  int*           bcount = (int*)(cnt + 64);                   // 128
  int*           bbase  = bcount + 128;                       // 128
  int*           bcur   = bbase + 128;                        // 128
  int*           row_off= bcur + 128;                         // N+1
  int*           csr_src= row_off + N + 1;                    // E+N
  unsigned*      packed = (unsigned*)(csr_src + E + N);       // E

  const int K    = (N + BK - 1) / BK;                    // dst buckets
  const int nch  = cdiv_l(E, EPB);                       // edge chunks

  // ---- build CSR by destination (bucket-partitioned; reused by all 5 layers) ----
  hipMemsetAsync(bcount, 0, 128 * 4, stream);
  bucket_hist_k<<<nch, TPB, 0, stream>>>(dst, bcount, E);
  bucket_scan_k<<<1, 128, 0, stream>>>(bcount, bbase, bcur, K);
  partition_k<<<nch, TPB, 0, stream>>>(src, dst, bcur, packed, E);
  bucket_csr_k<<<K, 256, 0, stream>>>(packed, bbase, bcur, row_off, csr_src, N, E, K);

  const int gb = cdiv_l(N, 4);

  // layer 1: Fin=128, H=1, C=32 (fp32 input)
  gemm2_k<128,32,32,float><<<cdiv_l(N, 1024/32), 256, 0, stream>>>(x, W_[0], as_[0], ad_[0], es, ed, Hb, N);
  agg_k<1,32><<<gb, 256, 0, stream>>>(csr_src, row_off, es, ed, Hb, b_[0], f_buf, N);
  // layer 2: Fin=32, H=2, C=32
  gemm2_k<32,64,32,ushort><<<cdiv_l(N, 1024/64), 256, 0, stream>>>(f_buf, W_[1], as_[1], ad_[1], es, ed, Hb, N);
  agg_k<2,32><<<gb, 256, 0, stream>>>(csr_src, row_off, es, ed, Hb, b_[1], f_buf, N);
  // layer 3: Fin=64, H=2, C=64
  gemm2_k<64,128,64,ushort><<<cdiv_l(N, 1024/128), 256, 0, stream>>>(f_buf, W_[2], as_[2], ad_[2], es, ed, Hb, N);
  agg_k<2,64><<<gb, 256, 0, stream>>>(csr_src, row_off, es, ed, Hb, b_[2], f_buf, N);
  // layer 4: Fin=128, H=2, C=32
  gemm2_k<128,64,32,ushort><<<cdiv_l(N, 1024/64), 256, 0, stream>>>(f_buf, W_[3], as_[3], ad_[3], es, ed, Hb, N);
  agg_k<2,32><<<gb, 256, 0, stream>>>(csr_src, row_off, es, ed, Hb, b_[3], f_buf, N);
  // layer 5: Fin=64, H=2, C=8
  gemm2_k<64,16,8,ushort><<<cdiv_l(N, 1024/16), 256, 0, stream>>>(f_buf, W_[4], as_[4], ad_[4], es, ed, Hb, N);
  agg_k<2,8><<<gb, 256, 0, stream>>>(csr_src, row_off, es, ed, Hb, b_[4], f_buf, N);

  // global mean pool (G=64) + FC + sigmoid
  hipMemsetAsync(pooled, 0, (64 * 16 + 64) * 4, stream);
  pool_k<<<64, 256, 0, stream>>>(f_buf, batch, pooled, cnt, N);
  final_fc_k<<<1, 64, 0, stream>>>(pooled, cnt, fcW, fcb, outp);
}